// Round 1
// baseline (1148.433 us; speedup 1.0000x reference)
//
#include <hip/hip_runtime.h>
#include <hip/hip_bf16.h>
#include <math.h>

#define N_NODES 50000
#define N_EDGES 800000
#define N_GRAPHS 64
#define IN_DIM 128
#define HID 32
#define HEADS 4
#define EDGE_DIM 8
#define OUT_DIM 10
#define HC 128          // HEADS*HID
#define NB 196          // ceil(N_NODES/256)

__device__ __forceinline__ float leaky(float x){ return x >= 0.f ? x : 0.2f*x; }
__device__ __forceinline__ float elu_f(float x){ return x > 0.f ? x : __expf(x)-1.f; }

// ---- CSR build ------------------------------------------------------------
__global__ __launch_bounds__(256) void k_hist(const int* __restrict__ dst, const float* __restrict__ eattr,
    int* __restrict__ cnt, float* __restrict__ loop_sum){
  int e = blockIdx.x*256 + threadIdx.x;
  if (e >= N_EDGES) return;
  int d = dst[e];
  atomicAdd(&cnt[d], 1);
  float4 x0 = *(const float4*)&eattr[e*8];
  float4 x1 = *(const float4*)&eattr[e*8+4];
  float* ls = &loop_sum[d*8];
  atomicAdd(ls+0,x0.x); atomicAdd(ls+1,x0.y); atomicAdd(ls+2,x0.z); atomicAdd(ls+3,x0.w);
  atomicAdd(ls+4,x1.x); atomicAdd(ls+5,x1.y); atomicAdd(ls+6,x1.z); atomicAdd(ls+7,x1.w);
}

__global__ __launch_bounds__(256) void k_blocksum(const int* __restrict__ cnt, int* __restrict__ bsum){
  __shared__ int sh[256];
  int n = blockIdx.x*256 + threadIdx.x;
  sh[threadIdx.x] = (n < N_NODES) ? cnt[n] : 0;
  __syncthreads();
  for (int off = 128; off > 0; off >>= 1){
    if (threadIdx.x < off) sh[threadIdx.x] += sh[threadIdx.x + off];
    __syncthreads();
  }
  if (threadIdx.x == 0) bsum[blockIdx.x] = sh[0];
}

__global__ __launch_bounds__(256) void k_scanb(const int* __restrict__ bsum, int* __restrict__ bpre){
  __shared__ int sh[256];
  int t = threadIdx.x;
  int v = (t < NB) ? bsum[t] : 0;
  sh[t] = v; __syncthreads();
  for (int off = 1; off < 256; off <<= 1){
    int u = (t >= off) ? sh[t-off] : 0;
    __syncthreads();
    sh[t] += u;
    __syncthreads();
  }
  if (t < NB) bpre[t] = sh[t] - v;
}

__global__ __launch_bounds__(256) void k_rowptr(const int* __restrict__ cnt, const int* __restrict__ bpre,
    int* __restrict__ rowptr){
  __shared__ int sh[256];
  int t = threadIdx.x; int n = blockIdx.x*256 + t;
  int c = (n < N_NODES) ? cnt[n] : 0;
  sh[t] = c; __syncthreads();
  for (int off = 1; off < 256; off <<= 1){
    int u = (t >= off) ? sh[t-off] : 0;
    __syncthreads();
    sh[t] += u;
    __syncthreads();
  }
  int incl = sh[t];
  if (n < N_NODES) rowptr[n] = bpre[blockIdx.x] + incl - c;
  if (n == N_NODES-1) rowptr[N_NODES] = bpre[blockIdx.x] + incl;
}

__global__ __launch_bounds__(256) void k_scatter(const int* __restrict__ src, const int* __restrict__ dst,
    const int* __restrict__ rowptr, int* __restrict__ wofs, int* __restrict__ s_src, int* __restrict__ s_eid){
  int e = blockIdx.x*256 + threadIdx.x;
  if (e >= N_EDGES) return;
  int d = dst[e];
  int pos = rowptr[d] + atomicAdd(&wofs[d], 1);
  s_src[pos] = src[e];
  s_eid[pos] = e;
}

// ---- edge-attention precompute -------------------------------------------
// v1[d][h] = sum_c We1[d,h*32+c]*att_e1[h,c]  (32 floats), v2[d] (8 floats)
__global__ void k_v(const float* __restrict__ We1, const float* __restrict__ ae1w,
                    const float* __restrict__ We2, const float* __restrict__ ae2w,
                    float* __restrict__ vbuf){
  int t = threadIdx.x;
  if (t < 32){
    int d = t >> 2, h = t & 3;
    float s = 0.f;
    for (int c = 0; c < 32; c++) s = fmaf(We1[d*128 + h*32 + c], ae1w[h*32 + c], s);
    vbuf[d*4 + h] = s;
  } else if (t < 40){
    int d = t - 32;
    float s = 0.f;
    for (int c = 0; c < 32; c++) s = fmaf(We2[d*32 + c], ae2w[c], s);
    vbuf[32 + d] = s;
  }
}

__global__ __launch_bounds__(256) void k_ae(const float* __restrict__ eattr, const float* __restrict__ vbuf,
    float* __restrict__ ae1, float* __restrict__ ae2){
  __shared__ float v[40];
  if (threadIdx.x < 40) v[threadIdx.x] = vbuf[threadIdx.x];
  __syncthreads();
  int e = blockIdx.x*256 + threadIdx.x;
  if (e >= N_EDGES) return;
  float4 x0 = *(const float4*)&eattr[e*8];
  float4 x1 = *(const float4*)&eattr[e*8+4];
  float ea[8] = {x0.x,x0.y,x0.z,x0.w,x1.x,x1.y,x1.z,x1.w};
  float4 r = make_float4(0,0,0,0);
  float r2 = 0.f;
  #pragma unroll
  for (int d = 0; d < 8; d++){
    r.x = fmaf(ea[d], v[d*4+0], r.x);
    r.y = fmaf(ea[d], v[d*4+1], r.y);
    r.z = fmaf(ea[d], v[d*4+2], r.z);
    r.w = fmaf(ea[d], v[d*4+3], r.w);
    r2  = fmaf(ea[d], v[32+d], r2);
  }
  *(float4*)&ae1[e*4] = r;
  ae2[e] = r2;
}

// self-loop attr = loop_sum/max(cnt,1); project to attention scalars
__global__ __launch_bounds__(256) void k_loop(const int* __restrict__ cnt, const float* __restrict__ loop_sum,
    const float* __restrict__ vbuf, float* __restrict__ ael1, float* __restrict__ ael2){
  __shared__ float v[40];
  if (threadIdx.x < 40) v[threadIdx.x] = vbuf[threadIdx.x];
  __syncthreads();
  int n = blockIdx.x*256 + threadIdx.x;
  if (n >= N_NODES) return;
  int cv = cnt[n]; if (cv < 1) cv = 1;
  float inv = 1.f / (float)cv;
  float4 r = make_float4(0,0,0,0); float r2 = 0.f;
  #pragma unroll
  for (int d = 0; d < 8; d++){
    float la = loop_sum[n*8 + d] * inv;
    r.x = fmaf(la, v[d*4+0], r.x);
    r.y = fmaf(la, v[d*4+1], r.y);
    r.z = fmaf(la, v[d*4+2], r.z);
    r.w = fmaf(la, v[d*4+3], r.w);
    r2  = fmaf(la, v[32+d], r2);
  }
  *(float4*)&ael1[n*4] = r;
  ael2[n] = r2;
}

// ---- GEMM1: h1 = x@W1 [N,128], + al_s1/al_d1 -----------------------------
// block=256, 16 nodes/block; wave j handles nodes base+j*4..+3, lane l -> c0=2l
__global__ __launch_bounds__(256) void k_gemm1(const float* __restrict__ x, const float* __restrict__ W1,
    const float* __restrict__ as1, const float* __restrict__ ad1,
    float* __restrict__ h1, float* __restrict__ als1, float* __restrict__ ald1){
  __shared__ float ws[64*128];   // 32 KB k-chunk of W1
  __shared__ float xs[16][128];  // 8 KB
  int t = threadIdx.x, l = t & 63, j = t >> 6;
  int c0 = l*2, h = l >> 4;
  int base = blockIdx.x * 16;
  float vs0 = as1[c0], vs1 = as1[c0+1], vd0 = ad1[c0], vd1 = ad1[c0+1];
  // stage x: 16 nodes x 128 = 512 float4s
  for (int i = t; i < 512; i += 256){
    int node = base + (i >> 5);
    int col = (i & 31) * 4;
    float4 v = make_float4(0,0,0,0);
    if (node < N_NODES) v = *(const float4*)&x[node*IN_DIM + col];
    *(float4*)&xs[i>>5][col] = v;
  }
  float acc[4][2];
  #pragma unroll
  for (int q = 0; q < 4; q++){ acc[q][0] = 0.f; acc[q][1] = 0.f; }
  for (int kb = 0; kb < 128; kb += 64){
    __syncthreads(); // xs visible (kb=0); ws reads of prev chunk done (kb=64)
    for (int i = t; i < 2048; i += 256)
      *(float4*)&ws[i*4] = *(const float4*)&W1[kb*128 + i*4];
    __syncthreads();
    for (int k = 0; k < 64; k++){
      float2 w = *(float2*)&ws[k*128 + c0];
      #pragma unroll
      for (int q = 0; q < 4; q++){
        float xv = xs[j*4+q][kb+k];
        acc[q][0] = fmaf(xv, w.x, acc[q][0]);
        acc[q][1] = fmaf(xv, w.y, acc[q][1]);
      }
    }
  }
  #pragma unroll
  for (int q = 0; q < 4; q++){
    int n = base + j*4 + q;
    if (n >= N_NODES) continue;   // uniform within wave
    float sa = fmaf(acc[q][0], vs0, acc[q][1]*vs1);
    float sd = fmaf(acc[q][0], vd0, acc[q][1]*vd1);
    #pragma unroll
    for (int off = 1; off < 16; off <<= 1){ sa += __shfl_xor(sa, off); sd += __shfl_xor(sd, off); }
    *(float2*)&h1[n*HC + c0] = make_float2(acc[q][0], acc[q][1]);
    if ((l & 15) == 0){ als1[n*4 + h] = sa; ald1[n*4 + h] = sd; }
  }
}

// ---- conv1 aggregation: one wave per node, online softmax ----------------
__global__ __launch_bounds__(256) void k_conv1(const int* __restrict__ rowptr, const int* __restrict__ s_src,
    const int* __restrict__ s_eid, const float* __restrict__ als1, const float* __restrict__ ald1,
    const float* __restrict__ ae1, const float* __restrict__ ael1, const float* __restrict__ h1,
    const float* __restrict__ b1, float* __restrict__ h_elu){
  int wv = threadIdx.x >> 6, l = threadIdx.x & 63;
  int n = blockIdx.x*4 + wv;
  if (n >= N_NODES) return;
  int c0 = l*2, h = l >> 4;
  float ad = ald1[n*4 + h];
  float m = leaky(als1[n*4 + h] + ad + ael1[n*4 + h]);  // self-loop
  float den = 1.f;
  float2 acc = *(const float2*)&h1[n*HC + c0];
  int r0 = rowptr[n], r1 = rowptr[n+1];
  for (int k = r0; k < r1; k++){
    int s = s_src[k], e = s_eid[k];
    float a = leaky(als1[s*4 + h] + ad + ae1[e*4 + h]);
    float2 hv = *(const float2*)&h1[s*HC + c0];
    float nm = fmaxf(m, a);
    float sm = __expf(m - nm), sa = __expf(a - nm);
    den = fmaf(den, sm, sa);
    acc.x = fmaf(acc.x, sm, sa*hv.x);
    acc.y = fmaf(acc.y, sm, sa*hv.y);
    m = nm;
  }
  float inv = 1.f / (den + 1e-16f);
  float o0 = fmaf(acc.x, inv, b1[c0]);
  float o1 = fmaf(acc.y, inv, b1[c0+1]);
  *(float2*)&h_elu[n*HC + c0] = make_float2(elu_f(o0), elu_f(o1));
}

// ---- GEMM2: h2 = h_elu@W2 [N,32], + al_s2/al_d2 --------------------------
__global__ __launch_bounds__(256) void k_gemm2(const float* __restrict__ hin, const float* __restrict__ W2,
    const float* __restrict__ as2, const float* __restrict__ ad2,
    float* __restrict__ h2, float* __restrict__ als2, float* __restrict__ ald2){
  __shared__ float ws[128*32];   // 16 KB full W2
  __shared__ float xs[16][128];  // 8 KB
  int t = threadIdx.x; int c = t & 31; int j = t >> 5;  // j: 0..7
  int base = blockIdx.x * 16;
  for (int i = t; i < 1024; i += 256)
    *(float4*)&ws[i*4] = *(const float4*)&W2[i*4];
  for (int i = t; i < 512; i += 256){
    int node = base + (i >> 5);
    int col = (i & 31) * 4;
    float4 v = make_float4(0,0,0,0);
    if (node < N_NODES) v = *(const float4*)&hin[node*128 + col];
    *(float4*)&xs[i>>5][col] = v;
  }
  __syncthreads();
  float s0 = 0.f, s1 = 0.f;
  for (int k = 0; k < 128; k++){
    float w = ws[k*32 + c];
    s0 = fmaf(xs[j*2][k],   w, s0);
    s1 = fmaf(xs[j*2+1][k], w, s1);
  }
  float a2c = as2[c], d2c = ad2[c];
  int n0 = base + j*2, n1 = n0 + 1;
  float sa0 = s0*a2c, sd0 = s0*d2c, sa1 = s1*a2c, sd1 = s1*d2c;
  #pragma unroll
  for (int off = 1; off < 32; off <<= 1){
    sa0 += __shfl_xor(sa0, off); sd0 += __shfl_xor(sd0, off);
    sa1 += __shfl_xor(sa1, off); sd1 += __shfl_xor(sd1, off);
  }
  if (n0 < N_NODES){ h2[n0*32 + c] = s0; if (c == 0){ als2[n0] = sa0; ald2[n0] = sd0; } }
  if (n1 < N_NODES){ h2[n1*32 + c] = s1; if (c == 0){ als2[n1] = sa1; ald2[n1] = sd1; } }
}

// ---- conv2 aggregation: one wave per node, half-wave edge split ----------
__global__ __launch_bounds__(256) void k_conv2(const int* __restrict__ rowptr, const int* __restrict__ s_src,
    const int* __restrict__ s_eid, const float* __restrict__ als2, const float* __restrict__ ald2,
    const float* __restrict__ ae2, const float* __restrict__ ael2, const float* __restrict__ h2,
    const float* __restrict__ b2, float* __restrict__ out2){
  int wv = threadIdx.x >> 6, l = threadIdx.x & 63;
  int n = blockIdx.x*4 + wv;
  if (n >= N_NODES) return;
  int half = l >> 5, c = l & 31;
  float ad = ald2[n];
  int r0 = rowptr[n], r1 = rowptr[n+1];
  int h0 = (r1 - r0 + 1) >> 1;
  float m, den, acc; int ks, ke;
  if (half == 0){
    m = leaky(als2[n] + ad + ael2[n]); den = 1.f; acc = h2[n*32 + c];
    ks = r0; ke = r0 + h0;
  } else {
    m = -INFINITY; den = 0.f; acc = 0.f;
    ks = r0 + h0; ke = r1;
  }
  for (int k = ks; k < ke; k++){
    int s = s_src[k], e = s_eid[k];
    float a = leaky(als2[s] + ad + ae2[e]);
    float hv = h2[s*32 + c];
    float nm = fmaxf(m, a);
    float sm = __expf(m - nm), sa = __expf(a - nm);
    den = fmaf(den, sm, sa);
    acc = fmaf(acc, sm, sa*hv);
    m = nm;
  }
  float mo = __shfl_xor(m, 32), deno = __shfl_xor(den, 32), acco = __shfl_xor(acc, 32);
  float nm = fmaxf(m, mo);
  float sm = __expf(m - nm), so = __expf(mo - nm);
  float dt = den*sm + deno*so;
  float at = acc*sm + acco*so;
  float val = at / (dt + 1e-16f) + b2[c];
  if (half == 0) out2[n*32 + c] = elu_f(val);
}

// ---- global mean pool (batch is sorted) ----------------------------------
__global__ __launch_bounds__(256) void k_pool(const float* __restrict__ out2, const int* __restrict__ batch,
    float* __restrict__ gpool){
  int g = blockIdx.x;
  int a = 0, b = N_NODES;
  while (a < b){ int mid = (a + b) >> 1; if (batch[mid] < g) a = mid + 1; else b = mid; }
  int lo = a;
  a = lo; b = N_NODES;
  while (a < b){ int mid = (a + b) >> 1; if (batch[mid] < g + 1) a = mid + 1; else b = mid; }
  int hi = a;
  int t = threadIdx.x, c = t & 31, r = t >> 5;
  float s = 0.f;
  for (int n = lo + r; n < hi; n += 8) s += out2[n*32 + c];
  __shared__ float sh[256];
  sh[t] = s; __syncthreads();
  if (r == 0){
    for (int q = 1; q < 8; q++) s += sh[q*32 + c];
    int cg = hi - lo; if (cg < 1) cg = 1;
    gpool[g*32 + c] = s / (float)cg;
  }
}

// ---- MLP head ------------------------------------------------------------
__global__ __launch_bounds__(1024) void k_mlp(const float* __restrict__ gpool, const float* __restrict__ W3,
    const float* __restrict__ b3, const float* __restrict__ W4, const float* __restrict__ b4,
    float* __restrict__ out){
  __shared__ float z[64*16];
  int t = threadIdx.x;
  {
    int g = t >> 4, jj = t & 15;
    float s = b3[jj];
    #pragma unroll
    for (int c = 0; c < 32; c++) s = fmaf(gpool[g*32 + c], W3[c*16 + jj], s);
    z[t] = fmaxf(s, 0.f);
  }
  __syncthreads();
  if (t < 640){
    int g = t / 10, o = t - g*10;
    float s = b4[o];
    #pragma unroll
    for (int jj = 0; jj < 16; jj++) s = fmaf(z[g*16 + jj], W4[jj*10 + o], s);
    out[t] = s;
  }
}

extern "C" void kernel_launch(void* const* d_in, const int* in_sizes, int n_in,
                              void* d_out, int out_size, void* d_ws, size_t ws_size,
                              hipStream_t stream) {
  (void)in_sizes; (void)n_in; (void)out_size; (void)ws_size;
  const float* x     = (const float*)d_in[0];
  const int*   ei    = (const int*)  d_in[1];
  const float* eattr = (const float*)d_in[2];
  const int*   batch = (const int*)  d_in[3];
  const float* W1    = (const float*)d_in[4];
  const float* as1   = (const float*)d_in[5];
  const float* ad1   = (const float*)d_in[6];
  const float* We1   = (const float*)d_in[7];
  const float* ae1w  = (const float*)d_in[8];
  const float* b1    = (const float*)d_in[9];
  const float* W2    = (const float*)d_in[10];
  const float* as2   = (const float*)d_in[11];
  const float* ad2   = (const float*)d_in[12];
  const float* We2   = (const float*)d_in[13];
  const float* ae2w  = (const float*)d_in[14];
  const float* b2    = (const float*)d_in[15];
  const float* W3    = (const float*)d_in[16];
  const float* b3    = (const float*)d_in[17];
  const float* W4    = (const float*)d_in[18];
  const float* b4    = (const float*)d_in[19];
  float* out = (float*)d_out;
  const int* src  = ei;
  const int* dstp = ei + N_EDGES;

  char* p = (char*)d_ws;
  auto alloc = [&](size_t bytes)->void*{ void* r = (void*)p; p += (bytes + 255) & ~(size_t)255; return r; };
  int*   cnt      = (int*)  alloc(4*N_NODES);
  int*   wofs     = (int*)  alloc(4*N_NODES);
  float* loop_sum = (float*)alloc(32*N_NODES);
  size_t zero_bytes = (size_t)(p - (char*)d_ws);   // cnt+wofs+loop_sum
  int*   rowptr   = (int*)  alloc(4*(N_NODES+1));
  int*   bsum     = (int*)  alloc(4*NB);
  int*   bpre     = (int*)  alloc(4*NB);
  int*   s_src    = (int*)  alloc(4*N_EDGES);
  int*   s_eid    = (int*)  alloc(4*N_EDGES);
  float* vbuf     = (float*)alloc(4*40);
  float* ae1      = (float*)alloc(16*N_EDGES);
  float* ae2      = (float*)alloc(4*N_EDGES);
  float* ael1     = (float*)alloc(16*N_NODES);
  float* ael2     = (float*)alloc(4*N_NODES);
  float* h1       = (float*)alloc(4*N_NODES*HC);
  float* als1     = (float*)alloc(16*N_NODES);
  float* ald1     = (float*)alloc(16*N_NODES);
  float* h_elu    = (float*)alloc(4*N_NODES*HC);
  float* h2       = (float*)alloc(4*N_NODES*HID);
  float* als2     = (float*)alloc(4*N_NODES);
  float* ald2     = (float*)alloc(4*N_NODES);
  float* out2     = (float*)alloc(4*N_NODES*HID);
  float* gpool    = (float*)alloc(4*N_GRAPHS*HID);

  const int EB = (N_EDGES + 255)/256;   // 3125

  hipMemsetAsync(d_ws, 0, zero_bytes, stream);
  k_v      <<<1,    64,  0, stream>>>(We1, ae1w, We2, ae2w, vbuf);
  k_hist   <<<EB,   256, 0, stream>>>(dstp, eattr, cnt, loop_sum);
  k_blocksum<<<NB,  256, 0, stream>>>(cnt, bsum);
  k_scanb  <<<1,    256, 0, stream>>>(bsum, bpre);
  k_rowptr <<<NB,   256, 0, stream>>>(cnt, bpre, rowptr);
  k_scatter<<<EB,   256, 0, stream>>>(src, dstp, rowptr, wofs, s_src, s_eid);
  k_ae     <<<EB,   256, 0, stream>>>(eattr, vbuf, ae1, ae2);
  k_loop   <<<NB,   256, 0, stream>>>(cnt, loop_sum, vbuf, ael1, ael2);
  k_gemm1  <<<(N_NODES+15)/16, 256, 0, stream>>>(x, W1, as1, ad1, h1, als1, ald1);
  k_conv1  <<<(N_NODES+3)/4,   256, 0, stream>>>(rowptr, s_src, s_eid, als1, ald1, ae1, ael1, h1, b1, h_elu);
  k_gemm2  <<<(N_NODES+15)/16, 256, 0, stream>>>(h_elu, W2, as2, ad2, h2, als2, ald2);
  k_conv2  <<<(N_NODES+3)/4,   256, 0, stream>>>(rowptr, s_src, s_eid, als2, ald2, ae2, ael2, h2, b2, out2);
  k_pool   <<<N_GRAPHS, 256, 0, stream>>>(out2, batch, gpool);
  k_mlp    <<<1,   1024, 0, stream>>>(gpool, W3, b3, W4, b4, out);
}

// Round 2
// 802.662 us; speedup vs baseline: 1.4308x; 1.4308x over previous
//
#include <hip/hip_runtime.h>
#include <hip/hip_bf16.h>
#include <math.h>

#define N_NODES 50000
#define N_EDGES 800000
#define N_GRAPHS 64
#define IN_DIM 128
#define HID 32
#define HEADS 4
#define EDGE_DIM 8
#define OUT_DIM 10
#define HC 128          // HEADS*HID
#define NB 196          // ceil(N_NODES/256)

__device__ __forceinline__ float leaky(float x){ return x >= 0.f ? x : 0.2f*x; }
__device__ __forceinline__ float elu_f(float x){ return x > 0.f ? x : __expf(x)-1.f; }

// ---- CSR build ------------------------------------------------------------
__global__ __launch_bounds__(256) void k_hist(const int* __restrict__ dst, const float* __restrict__ eattr,
    int* __restrict__ cnt, float* __restrict__ loop_sum){
  int e = blockIdx.x*256 + threadIdx.x;
  if (e >= N_EDGES) return;
  int d = dst[e];
  atomicAdd(&cnt[d], 1);
  float4 x0 = *(const float4*)&eattr[e*8];
  float4 x1 = *(const float4*)&eattr[e*8+4];
  float* ls = &loop_sum[d*8];
  atomicAdd(ls+0,x0.x); atomicAdd(ls+1,x0.y); atomicAdd(ls+2,x0.z); atomicAdd(ls+3,x0.w);
  atomicAdd(ls+4,x1.x); atomicAdd(ls+5,x1.y); atomicAdd(ls+6,x1.z); atomicAdd(ls+7,x1.w);
}

__global__ __launch_bounds__(256) void k_blocksum(const int* __restrict__ cnt, int* __restrict__ bsum){
  __shared__ int sh[256];
  int n = blockIdx.x*256 + threadIdx.x;
  sh[threadIdx.x] = (n < N_NODES) ? cnt[n] : 0;
  __syncthreads();
  for (int off = 128; off > 0; off >>= 1){
    if (threadIdx.x < off) sh[threadIdx.x] += sh[threadIdx.x + off];
    __syncthreads();
  }
  if (threadIdx.x == 0) bsum[blockIdx.x] = sh[0];
}

__global__ __launch_bounds__(256) void k_scanb(const int* __restrict__ bsum, int* __restrict__ bpre){
  __shared__ int sh[256];
  int t = threadIdx.x;
  int v = (t < NB) ? bsum[t] : 0;
  sh[t] = v; __syncthreads();
  for (int off = 1; off < 256; off <<= 1){
    int u = (t >= off) ? sh[t-off] : 0;
    __syncthreads();
    sh[t] += u;
    __syncthreads();
  }
  if (t < NB) bpre[t] = sh[t] - v;
}

__global__ __launch_bounds__(256) void k_rowptr(const int* __restrict__ cnt, const int* __restrict__ bpre,
    int* __restrict__ rowptr){
  __shared__ int sh[256];
  int t = threadIdx.x; int n = blockIdx.x*256 + t;
  int c = (n < N_NODES) ? cnt[n] : 0;
  sh[t] = c; __syncthreads();
  for (int off = 1; off < 256; off <<= 1){
    int u = (t >= off) ? sh[t-off] : 0;
    __syncthreads();
    sh[t] += u;
    __syncthreads();
  }
  int incl = sh[t];
  if (n < N_NODES) rowptr[n] = bpre[blockIdx.x] + incl - c;
  if (n == N_NODES-1) rowptr[N_NODES] = bpre[blockIdx.x] + incl;
}

__global__ __launch_bounds__(256) void k_scatter(const int* __restrict__ src, const int* __restrict__ dst,
    const int* __restrict__ rowptr, int* __restrict__ wofs, int* __restrict__ s_src, int* __restrict__ s_eid){
  int e = blockIdx.x*256 + threadIdx.x;
  if (e >= N_EDGES) return;
  int d = dst[e];
  int pos = rowptr[d] + atomicAdd(&wofs[d], 1);
  s_src[pos] = src[e];
  s_eid[pos] = e;
}

// ---- edge-attention precompute -------------------------------------------
// v1[d][h] = sum_c We1[d,h*32+c]*att_e1[h,c]  (32 floats), v2[d] (8 floats)
__global__ void k_v(const float* __restrict__ We1, const float* __restrict__ ae1w,
                    const float* __restrict__ We2, const float* __restrict__ ae2w,
                    float* __restrict__ vbuf){
  int t = threadIdx.x;
  if (t < 32){
    int d = t >> 2, h = t & 3;
    float s = 0.f;
    for (int c = 0; c < 32; c++) s = fmaf(We1[d*128 + h*32 + c], ae1w[h*32 + c], s);
    vbuf[d*4 + h] = s;
  } else if (t < 40){
    int d = t - 32;
    float s = 0.f;
    for (int c = 0; c < 32; c++) s = fmaf(We2[d*32 + c], ae2w[c], s);
    vbuf[32 + d] = s;
  }
}

__global__ __launch_bounds__(256) void k_ae(const float* __restrict__ eattr, const float* __restrict__ vbuf,
    float* __restrict__ ae1, float* __restrict__ ae2){
  __shared__ float v[40];
  if (threadIdx.x < 40) v[threadIdx.x] = vbuf[threadIdx.x];
  __syncthreads();
  int e = blockIdx.x*256 + threadIdx.x;
  if (e >= N_EDGES) return;
  float4 x0 = *(const float4*)&eattr[e*8];
  float4 x1 = *(const float4*)&eattr[e*8+4];
  float ea[8] = {x0.x,x0.y,x0.z,x0.w,x1.x,x1.y,x1.z,x1.w};
  float4 r = make_float4(0,0,0,0);
  float r2 = 0.f;
  #pragma unroll
  for (int d = 0; d < 8; d++){
    r.x = fmaf(ea[d], v[d*4+0], r.x);
    r.y = fmaf(ea[d], v[d*4+1], r.y);
    r.z = fmaf(ea[d], v[d*4+2], r.z);
    r.w = fmaf(ea[d], v[d*4+3], r.w);
    r2  = fmaf(ea[d], v[32+d], r2);
  }
  *(float4*)&ae1[e*4] = r;
  ae2[e] = r2;
}

// self-loop attr = loop_sum/max(cnt,1); project to attention scalars
__global__ __launch_bounds__(256) void k_loop(const int* __restrict__ cnt, const float* __restrict__ loop_sum,
    const float* __restrict__ vbuf, float* __restrict__ ael1, float* __restrict__ ael2){
  __shared__ float v[40];
  if (threadIdx.x < 40) v[threadIdx.x] = vbuf[threadIdx.x];
  __syncthreads();
  int n = blockIdx.x*256 + threadIdx.x;
  if (n >= N_NODES) return;
  int cv = cnt[n]; if (cv < 1) cv = 1;
  float inv = 1.f / (float)cv;
  float4 r = make_float4(0,0,0,0); float r2 = 0.f;
  #pragma unroll
  for (int d = 0; d < 8; d++){
    float la = loop_sum[n*8 + d] * inv;
    r.x = fmaf(la, v[d*4+0], r.x);
    r.y = fmaf(la, v[d*4+1], r.y);
    r.z = fmaf(la, v[d*4+2], r.z);
    r.w = fmaf(la, v[d*4+3], r.w);
    r2  = fmaf(la, v[32+d], r2);
  }
  *(float4*)&ael1[n*4] = r;
  ael2[n] = r2;
}

// ---- GEMM1: h1 = x@W1 [N,128], + al_s1/al_d1 -----------------------------
// 64 nodes/block, 256 threads. Thread tile: 4 nodes x 8 consecutive cols.
// acc[4][8]=32 VGPRs; per-k: 2x ds_read_b128 (W) + 4 broadcast scalar (x)
// feeding 32 FMAs. #pragma unroll 4 keeps the scheduler register-sane
// (previous version: compiler fully unrolled k=64, hit 256 VGPRs, spilled
// ~850 B/thread -> 1.05 GB HBM traffic, 405 us).
__global__ __launch_bounds__(256) void k_gemm1(const float* __restrict__ x, const float* __restrict__ W1,
    const float* __restrict__ as1, const float* __restrict__ ad1,
    float* __restrict__ h1, float* __restrict__ als1, float* __restrict__ ald1){
  __shared__ float xs[64][128];  // 32 KB
  __shared__ float ws[64*128];   // 32 KB (one 64-row K-chunk of W1)
  int t = threadIdx.x;
  int cg = t & 15;               // col group: cols c8..c8+7
  int c8 = cg * 8;
  int qb = (t >> 4) * 4;         // node sub-base: 16 groups x 4 nodes = 64
  int base = blockIdx.x * 64;
  // stage x: 64 nodes x 128 cols = 2048 float4
  for (int i = t; i < 2048; i += 256){
    int node = base + (i >> 5);
    int col = (i & 31) * 4;
    float4 v = make_float4(0,0,0,0);
    if (node < N_NODES) v = *(const float4*)&x[node*IN_DIM + col];
    *(float4*)&xs[i>>5][col] = v;
  }
  float acc[4][8];
  #pragma unroll
  for (int q = 0; q < 4; q++)
    #pragma unroll
    for (int i = 0; i < 8; i++) acc[q][i] = 0.f;

  for (int kb = 0; kb < 128; kb += 64){
    __syncthreads();  // xs ready (kb=0) / prev ws reads done (kb=64)
    for (int i = t; i < 2048; i += 256)
      *(float4*)&ws[i*4] = *(const float4*)&W1[kb*128 + i*4];
    __syncthreads();
    #pragma unroll 4
    for (int k = 0; k < 64; k++){
      float4 w0 = *(float4*)&ws[k*128 + c8];
      float4 w1 = *(float4*)&ws[k*128 + c8 + 4];
      #pragma unroll
      for (int q = 0; q < 4; q++){
        float xv = xs[qb + q][kb + k];
        acc[q][0] = fmaf(xv, w0.x, acc[q][0]);
        acc[q][1] = fmaf(xv, w0.y, acc[q][1]);
        acc[q][2] = fmaf(xv, w0.z, acc[q][2]);
        acc[q][3] = fmaf(xv, w0.w, acc[q][3]);
        acc[q][4] = fmaf(xv, w1.x, acc[q][4]);
        acc[q][5] = fmaf(xv, w1.y, acc[q][5]);
        acc[q][6] = fmaf(xv, w1.z, acc[q][6]);
        acc[q][7] = fmaf(xv, w1.w, acc[q][7]);
      }
    }
  }
  // epilogue: this thread's 8 cols all lie in head = cg>>2
  int head = cg >> 2;
  float asv[8], adv[8];
  #pragma unroll
  for (int i = 0; i < 8; i++){ asv[i] = as1[c8 + i]; adv[i] = ad1[c8 + i]; }
  #pragma unroll
  for (int q = 0; q < 4; q++){
    int n = base + qb + q;
    if (n >= N_NODES) continue;
    float sa = 0.f, sd = 0.f;
    #pragma unroll
    for (int i = 0; i < 8; i++){
      sa = fmaf(acc[q][i], asv[i], sa);
      sd = fmaf(acc[q][i], adv[i], sd);
    }
    // reduce over the 4 lanes (cg&3) sharing this head (lane bits 0-1)
    sa += __shfl_xor(sa, 1); sd += __shfl_xor(sd, 1);
    sa += __shfl_xor(sa, 2); sd += __shfl_xor(sd, 2);
    *(float4*)&h1[n*HC + c8]     = make_float4(acc[q][0], acc[q][1], acc[q][2], acc[q][3]);
    *(float4*)&h1[n*HC + c8 + 4] = make_float4(acc[q][4], acc[q][5], acc[q][6], acc[q][7]);
    if ((cg & 3) == 0){ als1[n*4 + head] = sa; ald1[n*4 + head] = sd; }
  }
}

// ---- conv1 aggregation: one wave per node, online softmax ----------------
__global__ __launch_bounds__(256) void k_conv1(const int* __restrict__ rowptr, const int* __restrict__ s_src,
    const int* __restrict__ s_eid, const float* __restrict__ als1, const float* __restrict__ ald1,
    const float* __restrict__ ae1, const float* __restrict__ ael1, const float* __restrict__ h1,
    const float* __restrict__ b1, float* __restrict__ h_elu){
  int wv = threadIdx.x >> 6, l = threadIdx.x & 63;
  int n = blockIdx.x*4 + wv;
  if (n >= N_NODES) return;
  int c0 = l*2, h = l >> 4;
  float ad = ald1[n*4 + h];
  float m = leaky(als1[n*4 + h] + ad + ael1[n*4 + h]);  // self-loop
  float den = 1.f;
  float2 acc = *(const float2*)&h1[n*HC + c0];
  int r0 = rowptr[n], r1 = rowptr[n+1];
  for (int k = r0; k < r1; k++){
    int s = s_src[k], e = s_eid[k];
    float a = leaky(als1[s*4 + h] + ad + ae1[e*4 + h]);
    float2 hv = *(const float2*)&h1[s*HC + c0];
    float nm = fmaxf(m, a);
    float sm = __expf(m - nm), sa = __expf(a - nm);
    den = fmaf(den, sm, sa);
    acc.x = fmaf(acc.x, sm, sa*hv.x);
    acc.y = fmaf(acc.y, sm, sa*hv.y);
    m = nm;
  }
  float inv = 1.f / (den + 1e-16f);
  float o0 = fmaf(acc.x, inv, b1[c0]);
  float o1 = fmaf(acc.y, inv, b1[c0+1]);
  *(float2*)&h_elu[n*HC + c0] = make_float2(elu_f(o0), elu_f(o1));
}

// ---- GEMM2: h2 = h_elu@W2 [N,32], + al_s2/al_d2 --------------------------
__global__ __launch_bounds__(256) void k_gemm2(const float* __restrict__ hin, const float* __restrict__ W2,
    const float* __restrict__ as2, const float* __restrict__ ad2,
    float* __restrict__ h2, float* __restrict__ als2, float* __restrict__ ald2){
  __shared__ float ws[128*32];   // 16 KB full W2
  __shared__ float xs[16][128];  // 8 KB
  int t = threadIdx.x; int c = t & 31; int j = t >> 5;  // j: 0..7
  int base = blockIdx.x * 16;
  for (int i = t; i < 1024; i += 256)
    *(float4*)&ws[i*4] = *(const float4*)&W2[i*4];
  for (int i = t; i < 512; i += 256){
    int node = base + (i >> 5);
    int col = (i & 31) * 4;
    float4 v = make_float4(0,0,0,0);
    if (node < N_NODES) v = *(const float4*)&hin[node*128 + col];
    *(float4*)&xs[i>>5][col] = v;
  }
  __syncthreads();
  float s0 = 0.f, s1 = 0.f;
  #pragma unroll 8
  for (int k = 0; k < 128; k++){
    float w = ws[k*32 + c];
    s0 = fmaf(xs[j*2][k],   w, s0);
    s1 = fmaf(xs[j*2+1][k], w, s1);
  }
  float a2c = as2[c], d2c = ad2[c];
  int n0 = base + j*2, n1 = n0 + 1;
  float sa0 = s0*a2c, sd0 = s0*d2c, sa1 = s1*a2c, sd1 = s1*d2c;
  #pragma unroll
  for (int off = 1; off < 32; off <<= 1){
    sa0 += __shfl_xor(sa0, off); sd0 += __shfl_xor(sd0, off);
    sa1 += __shfl_xor(sa1, off); sd1 += __shfl_xor(sd1, off);
  }
  if (n0 < N_NODES){ h2[n0*32 + c] = s0; if (c == 0){ als2[n0] = sa0; ald2[n0] = sd0; } }
  if (n1 < N_NODES){ h2[n1*32 + c] = s1; if (c == 0){ als2[n1] = sa1; ald2[n1] = sd1; } }
}

// ---- conv2 aggregation: one wave per node, half-wave edge split ----------
__global__ __launch_bounds__(256) void k_conv2(const int* __restrict__ rowptr, const int* __restrict__ s_src,
    const int* __restrict__ s_eid, const float* __restrict__ als2, const float* __restrict__ ald2,
    const float* __restrict__ ae2, const float* __restrict__ ael2, const float* __restrict__ h2,
    const float* __restrict__ b2, float* __restrict__ out2){
  int wv = threadIdx.x >> 6, l = threadIdx.x & 63;
  int n = blockIdx.x*4 + wv;
  if (n >= N_NODES) return;
  int half = l >> 5, c = l & 31;
  float ad = ald2[n];
  int r0 = rowptr[n], r1 = rowptr[n+1];
  int h0 = (r1 - r0 + 1) >> 1;
  float m, den, acc; int ks, ke;
  if (half == 0){
    m = leaky(als2[n] + ad + ael2[n]); den = 1.f; acc = h2[n*32 + c];
    ks = r0; ke = r0 + h0;
  } else {
    m = -INFINITY; den = 0.f; acc = 0.f;
    ks = r0 + h0; ke = r1;
  }
  for (int k = ks; k < ke; k++){
    int s = s_src[k], e = s_eid[k];
    float a = leaky(als2[s] + ad + ae2[e]);
    float hv = h2[s*32 + c];
    float nm = fmaxf(m, a);
    float sm = __expf(m - nm), sa = __expf(a - nm);
    den = fmaf(den, sm, sa);
    acc = fmaf(acc, sm, sa*hv);
    m = nm;
  }
  float mo = __shfl_xor(m, 32), deno = __shfl_xor(den, 32), acco = __shfl_xor(acc, 32);
  float nm = fmaxf(m, mo);
  float sm = __expf(m - nm), so = __expf(mo - nm);
  float dt = den*sm + deno*so;
  float at = acc*sm + acco*so;
  float val = at / (dt + 1e-16f) + b2[c];
  if (half == 0) out2[n*32 + c] = elu_f(val);
}

// ---- global mean pool (batch is sorted) ----------------------------------
__global__ __launch_bounds__(256) void k_pool(const float* __restrict__ out2, const int* __restrict__ batch,
    float* __restrict__ gpool){
  int g = blockIdx.x;
  int a = 0, b = N_NODES;
  while (a < b){ int mid = (a + b) >> 1; if (batch[mid] < g) a = mid + 1; else b = mid; }
  int lo = a;
  a = lo; b = N_NODES;
  while (a < b){ int mid = (a + b) >> 1; if (batch[mid] < g + 1) a = mid + 1; else b = mid; }
  int hi = a;
  int t = threadIdx.x, c = t & 31, r = t >> 5;
  float s = 0.f;
  for (int n = lo + r; n < hi; n += 8) s += out2[n*32 + c];
  __shared__ float sh[256];
  sh[t] = s; __syncthreads();
  if (r == 0){
    for (int q = 1; q < 8; q++) s += sh[q*32 + c];
    int cg = hi - lo; if (cg < 1) cg = 1;
    gpool[g*32 + c] = s / (float)cg;
  }
}

// ---- MLP head ------------------------------------------------------------
__global__ __launch_bounds__(1024) void k_mlp(const float* __restrict__ gpool, const float* __restrict__ W3,
    const float* __restrict__ b3, const float* __restrict__ W4, const float* __restrict__ b4,
    float* __restrict__ out){
  __shared__ float z[64*16];
  int t = threadIdx.x;
  {
    int g = t >> 4, jj = t & 15;
    float s = b3[jj];
    #pragma unroll
    for (int c = 0; c < 32; c++) s = fmaf(gpool[g*32 + c], W3[c*16 + jj], s);
    z[t] = fmaxf(s, 0.f);
  }
  __syncthreads();
  if (t < 640){
    int g = t / 10, o = t - g*10;
    float s = b4[o];
    #pragma unroll
    for (int jj = 0; jj < 16; jj++) s = fmaf(z[g*16 + jj], W4[jj*10 + o], s);
    out[t] = s;
  }
}

extern "C" void kernel_launch(void* const* d_in, const int* in_sizes, int n_in,
                              void* d_out, int out_size, void* d_ws, size_t ws_size,
                              hipStream_t stream) {
  (void)in_sizes; (void)n_in; (void)out_size; (void)ws_size;
  const float* x     = (const float*)d_in[0];
  const int*   ei    = (const int*)  d_in[1];
  const float* eattr = (const float*)d_in[2];
  const int*   batch = (const int*)  d_in[3];
  const float* W1    = (const float*)d_in[4];
  const float* as1   = (const float*)d_in[5];
  const float* ad1   = (const float*)d_in[6];
  const float* We1   = (const float*)d_in[7];
  const float* ae1w  = (const float*)d_in[8];
  const float* b1    = (const float*)d_in[9];
  const float* W2    = (const float*)d_in[10];
  const float* as2   = (const float*)d_in[11];
  const float* ad2   = (const float*)d_in[12];
  const float* We2   = (const float*)d_in[13];
  const float* ae2w  = (const float*)d_in[14];
  const float* b2    = (const float*)d_in[15];
  const float* W3    = (const float*)d_in[16];
  const float* b3    = (const float*)d_in[17];
  const float* W4    = (const float*)d_in[18];
  const float* b4    = (const float*)d_in[19];
  float* out = (float*)d_out;
  const int* src  = ei;
  const int* dstp = ei + N_EDGES;

  char* p = (char*)d_ws;
  auto alloc = [&](size_t bytes)->void*{ void* r = (void*)p; p += (bytes + 255) & ~(size_t)255; return r; };
  int*   cnt      = (int*)  alloc(4*N_NODES);
  int*   wofs     = (int*)  alloc(4*N_NODES);
  float* loop_sum = (float*)alloc(32*N_NODES);
  size_t zero_bytes = (size_t)(p - (char*)d_ws);   // cnt+wofs+loop_sum
  int*   rowptr   = (int*)  alloc(4*(N_NODES+1));
  int*   bsum     = (int*)  alloc(4*NB);
  int*   bpre     = (int*)  alloc(4*NB);
  int*   s_src    = (int*)  alloc(4*N_EDGES);
  int*   s_eid    = (int*)  alloc(4*N_EDGES);
  float* vbuf     = (float*)alloc(4*40);
  float* ae1      = (float*)alloc(16*N_EDGES);
  float* ae2      = (float*)alloc(4*N_EDGES);
  float* ael1     = (float*)alloc(16*N_NODES);
  float* ael2     = (float*)alloc(4*N_NODES);
  float* h1       = (float*)alloc(4*N_NODES*HC);
  float* als1     = (float*)alloc(16*N_NODES);
  float* ald1     = (float*)alloc(16*N_NODES);
  float* h_elu    = (float*)alloc(4*N_NODES*HC);
  float* h2       = (float*)alloc(4*N_NODES*HID);
  float* als2     = (float*)alloc(4*N_NODES);
  float* ald2     = (float*)alloc(4*N_NODES);
  float* out2     = (float*)alloc(4*N_NODES*HID);
  float* gpool    = (float*)alloc(4*N_GRAPHS*HID);

  const int EB = (N_EDGES + 255)/256;   // 3125

  hipMemsetAsync(d_ws, 0, zero_bytes, stream);
  k_v      <<<1,    64,  0, stream>>>(We1, ae1w, We2, ae2w, vbuf);
  k_hist   <<<EB,   256, 0, stream>>>(dstp, eattr, cnt, loop_sum);
  k_blocksum<<<NB,  256, 0, stream>>>(cnt, bsum);
  k_scanb  <<<1,    256, 0, stream>>>(bsum, bpre);
  k_rowptr <<<NB,   256, 0, stream>>>(cnt, bpre, rowptr);
  k_scatter<<<EB,   256, 0, stream>>>(src, dstp, rowptr, wofs, s_src, s_eid);
  k_ae     <<<EB,   256, 0, stream>>>(eattr, vbuf, ae1, ae2);
  k_loop   <<<NB,   256, 0, stream>>>(cnt, loop_sum, vbuf, ael1, ael2);
  k_gemm1  <<<(N_NODES+63)/64, 256, 0, stream>>>(x, W1, as1, ad1, h1, als1, ald1);
  k_conv1  <<<(N_NODES+3)/4,   256, 0, stream>>>(rowptr, s_src, s_eid, als1, ald1, ae1, ael1, h1, b1, h_elu);
  k_gemm2  <<<(N_NODES+15)/16, 256, 0, stream>>>(h_elu, W2, as2, ad2, h2, als2, ald2);
  k_conv2  <<<(N_NODES+3)/4,   256, 0, stream>>>(rowptr, s_src, s_eid, als2, ald2, ae2, ael2, h2, b2, out2);
  k_pool   <<<N_GRAPHS, 256, 0, stream>>>(out2, batch, gpool);
  k_mlp    <<<1,   1024, 0, stream>>>(gpool, W3, b3, W4, b4, out);
}

// Round 3
// 463.886 us; speedup vs baseline: 2.4757x; 1.7303x over previous
//
#include <hip/hip_runtime.h>
#include <hip/hip_bf16.h>
#include <math.h>

#define N_NODES 50000
#define N_EDGES 800000
#define N_GRAPHS 64
#define IN_DIM 128
#define HID 32
#define HEADS 4
#define EDGE_DIM 8
#define OUT_DIM 10
#define HC 128          // HEADS*HID
#define NB 196          // ceil(N_NODES/256)

__device__ __forceinline__ float leaky(float x){ return x >= 0.f ? x : 0.2f*x; }
__device__ __forceinline__ float elu_f(float x){ return x > 0.f ? x : __expf(x)-1.f; }

// ---- degree histogram: ONE int atomic per edge ---------------------------
// (previous version also did 8 float atomicAdds/edge for loop_sum ->
//  7.2M device-scope RMWs, 225 MB HBM write traffic, 359 us. The self-loop
//  attr is only consumed through the LINEAR projection eattr.v, so the
//  mean is now folded into the conv kernels as sum(ae)/cnt.)
__global__ __launch_bounds__(256) void k_hist(const int* __restrict__ dst, int* __restrict__ cnt){
  int e = blockIdx.x*256 + threadIdx.x;
  if (e >= N_EDGES) return;
  atomicAdd(&cnt[dst[e]], 1);
}

__global__ __launch_bounds__(256) void k_blocksum(const int* __restrict__ cnt, int* __restrict__ bsum){
  __shared__ int sh[256];
  int n = blockIdx.x*256 + threadIdx.x;
  sh[threadIdx.x] = (n < N_NODES) ? cnt[n] : 0;
  __syncthreads();
  for (int off = 128; off > 0; off >>= 1){
    if (threadIdx.x < off) sh[threadIdx.x] += sh[threadIdx.x + off];
    __syncthreads();
  }
  if (threadIdx.x == 0) bsum[blockIdx.x] = sh[0];
}

__global__ __launch_bounds__(256) void k_scanb(const int* __restrict__ bsum, int* __restrict__ bpre){
  __shared__ int sh[256];
  int t = threadIdx.x;
  int v = (t < NB) ? bsum[t] : 0;
  sh[t] = v; __syncthreads();
  for (int off = 1; off < 256; off <<= 1){
    int u = (t >= off) ? sh[t-off] : 0;
    __syncthreads();
    sh[t] += u;
    __syncthreads();
  }
  if (t < NB) bpre[t] = sh[t] - v;
}

// rowptr + seed wofs = rowptr (scatter then atomically bumps wofs directly,
// no separate rowptr read needed)
__global__ __launch_bounds__(256) void k_rowptr(const int* __restrict__ cnt, const int* __restrict__ bpre,
    int* __restrict__ rowptr, int* __restrict__ wofs){
  __shared__ int sh[256];
  int t = threadIdx.x; int n = blockIdx.x*256 + t;
  int c = (n < N_NODES) ? cnt[n] : 0;
  sh[t] = c; __syncthreads();
  for (int off = 1; off < 256; off <<= 1){
    int u = (t >= off) ? sh[t-off] : 0;
    __syncthreads();
    sh[t] += u;
    __syncthreads();
  }
  int incl = sh[t];
  if (n < N_NODES){
    int rp = bpre[blockIdx.x] + incl - c;
    rowptr[n] = rp;
    wofs[n] = rp;
  }
  if (n == N_NODES-1) rowptr[N_NODES] = bpre[blockIdx.x] + incl;
}

// v1[d][h] = sum_c We1[d,h*32+c]*att_e1[h,c]  (32 floats), v2[d] (8 floats)
__global__ void k_v(const float* __restrict__ We1, const float* __restrict__ ae1w,
                    const float* __restrict__ We2, const float* __restrict__ ae2w,
                    float* __restrict__ vbuf){
  int t = threadIdx.x;
  if (t < 32){
    int d = t >> 2, h = t & 3;
    float s = 0.f;
    for (int c = 0; c < 32; c++) s = fmaf(We1[d*128 + h*32 + c], ae1w[h*32 + c], s);
    vbuf[d*4 + h] = s;
  } else if (t < 40){
    int d = t - 32;
    float s = 0.f;
    for (int c = 0; c < 32; c++) s = fmaf(We2[d*32 + c], ae2w[c], s);
    vbuf[32 + d] = s;
  }
}

// ---- scatter (CSR fill) fused with per-edge attention scalars ------------
__global__ __launch_bounds__(256) void k_scatter(const int* __restrict__ src, const int* __restrict__ dst,
    const float* __restrict__ eattr, const float* __restrict__ vbuf,
    int* __restrict__ wofs, int2* __restrict__ s_pack,
    float* __restrict__ ae1, float* __restrict__ ae2){
  __shared__ float v[40];
  if (threadIdx.x < 40) v[threadIdx.x] = vbuf[threadIdx.x];
  __syncthreads();
  int e = blockIdx.x*256 + threadIdx.x;
  if (e >= N_EDGES) return;
  int d = dst[e];
  int pos = atomicAdd(&wofs[d], 1);
  s_pack[pos] = make_int2(src[e], e);
  float4 x0 = *(const float4*)&eattr[e*8];
  float4 x1 = *(const float4*)&eattr[e*8+4];
  float ea[8] = {x0.x,x0.y,x0.z,x0.w,x1.x,x1.y,x1.z,x1.w};
  float4 r = make_float4(0,0,0,0);
  float r2 = 0.f;
  #pragma unroll
  for (int dd = 0; dd < 8; dd++){
    r.x = fmaf(ea[dd], v[dd*4+0], r.x);
    r.y = fmaf(ea[dd], v[dd*4+1], r.y);
    r.z = fmaf(ea[dd], v[dd*4+2], r.z);
    r.w = fmaf(ea[dd], v[dd*4+3], r.w);
    r2  = fmaf(ea[dd], v[32+dd], r2);
  }
  *(float4*)&ae1[e*4] = r;
  ae2[e] = r2;
}

// ---- GEMM1: h1 = x@W1 [N,128], + al_s1/al_d1 -----------------------------
__global__ __launch_bounds__(256) void k_gemm1(const float* __restrict__ x, const float* __restrict__ W1,
    const float* __restrict__ as1, const float* __restrict__ ad1,
    float* __restrict__ h1, float* __restrict__ als1, float* __restrict__ ald1){
  __shared__ float xs[64][128];  // 32 KB
  __shared__ float ws[64*128];   // 32 KB (one 64-row K-chunk of W1)
  int t = threadIdx.x;
  int cg = t & 15;               // col group: cols c8..c8+7
  int c8 = cg * 8;
  int qb = (t >> 4) * 4;         // node sub-base
  int base = blockIdx.x * 64;
  for (int i = t; i < 2048; i += 256){
    int node = base + (i >> 5);
    int col = (i & 31) * 4;
    float4 v = make_float4(0,0,0,0);
    if (node < N_NODES) v = *(const float4*)&x[node*IN_DIM + col];
    *(float4*)&xs[i>>5][col] = v;
  }
  float acc[4][8];
  #pragma unroll
  for (int q = 0; q < 4; q++)
    #pragma unroll
    for (int i = 0; i < 8; i++) acc[q][i] = 0.f;

  for (int kb = 0; kb < 128; kb += 64){
    __syncthreads();
    for (int i = t; i < 2048; i += 256)
      *(float4*)&ws[i*4] = *(const float4*)&W1[kb*128 + i*4];
    __syncthreads();
    #pragma unroll 4
    for (int k = 0; k < 64; k++){
      float4 w0 = *(float4*)&ws[k*128 + c8];
      float4 w1 = *(float4*)&ws[k*128 + c8 + 4];
      #pragma unroll
      for (int q = 0; q < 4; q++){
        float xv = xs[qb + q][kb + k];
        acc[q][0] = fmaf(xv, w0.x, acc[q][0]);
        acc[q][1] = fmaf(xv, w0.y, acc[q][1]);
        acc[q][2] = fmaf(xv, w0.z, acc[q][2]);
        acc[q][3] = fmaf(xv, w0.w, acc[q][3]);
        acc[q][4] = fmaf(xv, w1.x, acc[q][4]);
        acc[q][5] = fmaf(xv, w1.y, acc[q][5]);
        acc[q][6] = fmaf(xv, w1.z, acc[q][6]);
        acc[q][7] = fmaf(xv, w1.w, acc[q][7]);
      }
    }
  }
  int head = cg >> 2;
  float asv[8], adv[8];
  #pragma unroll
  for (int i = 0; i < 8; i++){ asv[i] = as1[c8 + i]; adv[i] = ad1[c8 + i]; }
  #pragma unroll
  for (int q = 0; q < 4; q++){
    int n = base + qb + q;
    if (n >= N_NODES) continue;
    float sa = 0.f, sd = 0.f;
    #pragma unroll
    for (int i = 0; i < 8; i++){
      sa = fmaf(acc[q][i], asv[i], sa);
      sd = fmaf(acc[q][i], adv[i], sd);
    }
    sa += __shfl_xor(sa, 1); sd += __shfl_xor(sd, 1);
    sa += __shfl_xor(sa, 2); sd += __shfl_xor(sd, 2);
    *(float4*)&h1[n*HC + c8]     = make_float4(acc[q][0], acc[q][1], acc[q][2], acc[q][3]);
    *(float4*)&h1[n*HC + c8 + 4] = make_float4(acc[q][4], acc[q][5], acc[q][6], acc[q][7]);
    if ((cg & 3) == 0){ als1[n*4 + head] = sa; ald1[n*4 + head] = sd; }
  }
}

// ---- conv1 aggregation: one wave per node, online softmax ----------------
// self-loop folded in at the end: a_self = leaky(als+ad+sum(ae)/cnt)
__global__ __launch_bounds__(256) void k_conv1(const int* __restrict__ rowptr, const int2* __restrict__ s_pack,
    const float* __restrict__ als1, const float* __restrict__ ald1,
    const float* __restrict__ ae1, const float* __restrict__ h1,
    const float* __restrict__ b1, float* __restrict__ h_elu){
  int wv = threadIdx.x >> 6, l = threadIdx.x & 63;
  int n = blockIdx.x*4 + wv;
  if (n >= N_NODES) return;
  int c0 = l*2, h = l >> 4;
  float ad = ald1[n*4 + h];
  float m = -1e30f, den = 0.f, sum_ae = 0.f;
  float2 acc = make_float2(0.f, 0.f);
  int r0 = rowptr[n], r1 = rowptr[n+1];
  for (int k = r0; k < r1; k++){
    int2 se = s_pack[k];
    float aev = ae1[se.y*4 + h];
    sum_ae += aev;
    float a = leaky(als1[se.x*4 + h] + ad + aev);
    float2 hv = *(const float2*)&h1[se.x*HC + c0];
    float nm = fmaxf(m, a);
    float sm = __expf(m - nm), sa = __expf(a - nm);
    den = fmaf(den, sm, sa);
    acc.x = fmaf(acc.x, sm, sa*hv.x);
    acc.y = fmaf(acc.y, sm, sa*hv.y);
    m = nm;
  }
  int cn = r1 - r0; if (cn < 1) cn = 1;
  float aself = leaky(als1[n*4 + h] + ad + sum_ae / (float)cn);
  float2 hself = *(const float2*)&h1[n*HC + c0];
  float nm = fmaxf(m, aself);
  float sm = __expf(m - nm), sa = __expf(aself - nm);
  den = fmaf(den, sm, sa);
  acc.x = fmaf(acc.x, sm, sa*hself.x);
  acc.y = fmaf(acc.y, sm, sa*hself.y);
  float inv = 1.f / (den + 1e-16f);
  float o0 = fmaf(acc.x, inv, b1[c0]);
  float o1 = fmaf(acc.y, inv, b1[c0+1]);
  *(float2*)&h_elu[n*HC + c0] = make_float2(elu_f(o0), elu_f(o1));
}

// ---- GEMM2: h2 = h_elu@W2 [N,32], + al_s2/al_d2 --------------------------
__global__ __launch_bounds__(256) void k_gemm2(const float* __restrict__ hin, const float* __restrict__ W2,
    const float* __restrict__ as2, const float* __restrict__ ad2,
    float* __restrict__ h2, float* __restrict__ als2, float* __restrict__ ald2){
  __shared__ float ws[128*32];   // 16 KB full W2
  __shared__ float xs[16][128];  // 8 KB
  int t = threadIdx.x; int c = t & 31; int j = t >> 5;  // j: 0..7
  int base = blockIdx.x * 16;
  for (int i = t; i < 1024; i += 256)
    *(float4*)&ws[i*4] = *(const float4*)&W2[i*4];
  for (int i = t; i < 512; i += 256){
    int node = base + (i >> 5);
    int col = (i & 31) * 4;
    float4 v = make_float4(0,0,0,0);
    if (node < N_NODES) v = *(const float4*)&hin[node*128 + col];
    *(float4*)&xs[i>>5][col] = v;
  }
  __syncthreads();
  float s0 = 0.f, s1 = 0.f;
  #pragma unroll 8
  for (int k = 0; k < 128; k++){
    float w = ws[k*32 + c];
    s0 = fmaf(xs[j*2][k],   w, s0);
    s1 = fmaf(xs[j*2+1][k], w, s1);
  }
  float a2c = as2[c], d2c = ad2[c];
  int n0 = base + j*2, n1 = n0 + 1;
  float sa0 = s0*a2c, sd0 = s0*d2c, sa1 = s1*a2c, sd1 = s1*d2c;
  #pragma unroll
  for (int off = 1; off < 32; off <<= 1){
    sa0 += __shfl_xor(sa0, off); sd0 += __shfl_xor(sd0, off);
    sa1 += __shfl_xor(sa1, off); sd1 += __shfl_xor(sd1, off);
  }
  if (n0 < N_NODES){ h2[n0*32 + c] = s0; if (c == 0){ als2[n0] = sa0; ald2[n0] = sd0; } }
  if (n1 < N_NODES){ h2[n1*32 + c] = s1; if (c == 0){ als2[n1] = sa1; ald2[n1] = sd1; } }
}

// ---- conv2 aggregation: one wave per node, half-wave edge split ----------
__global__ __launch_bounds__(256) void k_conv2(const int* __restrict__ rowptr, const int2* __restrict__ s_pack,
    const float* __restrict__ als2, const float* __restrict__ ald2,
    const float* __restrict__ ae2, const float* __restrict__ h2,
    const float* __restrict__ b2, float* __restrict__ out2){
  int wv = threadIdx.x >> 6, l = threadIdx.x & 63;
  int n = blockIdx.x*4 + wv;
  if (n >= N_NODES) return;
  int half = l >> 5, c = l & 31;
  float ad = ald2[n];
  int r0 = rowptr[n], r1 = rowptr[n+1];
  int h0 = (r1 - r0 + 1) >> 1;
  int ks = half ? r0 + h0 : r0;
  int ke = half ? r1 : r0 + h0;
  float m = -1e30f, den = 0.f, acc = 0.f, sum_ae = 0.f;
  for (int k = ks; k < ke; k++){
    int2 se = s_pack[k];
    float aev = ae2[se.y];
    sum_ae += aev;
    float a = leaky(als2[se.x] + ad + aev);
    float hv = h2[se.x*32 + c];
    float nm = fmaxf(m, a);
    float sm = __expf(m - nm), sa = __expf(a - nm);
    den = fmaf(den, sm, sa);
    acc = fmaf(acc, sm, sa*hv);
    m = nm;
  }
  // merge halves
  float mo = __shfl_xor(m, 32), deno = __shfl_xor(den, 32), acco = __shfl_xor(acc, 32);
  sum_ae += __shfl_xor(sum_ae, 32);
  float nm = fmaxf(m, mo);
  float sm = __expf(m - nm), so = __expf(mo - nm);
  den = den*sm + deno*so;
  acc = acc*sm + acco*so;
  m = nm;
  // merge self-loop element
  int cn = r1 - r0; if (cn < 1) cn = 1;
  float aself = leaky(als2[n] + ad + sum_ae / (float)cn);
  float hself = h2[n*32 + c];
  nm = fmaxf(m, aself);
  float s1 = __expf(m - nm), s2 = __expf(aself - nm);
  den = fmaf(den, s1, s2);
  acc = fmaf(acc, s1, s2*hself);
  float val = acc / (den + 1e-16f) + b2[c];
  if (half == 0) out2[n*32 + c] = elu_f(val);
}

// ---- global mean pool (batch is sorted) ----------------------------------
__global__ __launch_bounds__(256) void k_pool(const float* __restrict__ out2, const int* __restrict__ batch,
    float* __restrict__ gpool){
  int g = blockIdx.x;
  int a = 0, b = N_NODES;
  while (a < b){ int mid = (a + b) >> 1; if (batch[mid] < g) a = mid + 1; else b = mid; }
  int lo = a;
  a = lo; b = N_NODES;
  while (a < b){ int mid = (a + b) >> 1; if (batch[mid] < g + 1) a = mid + 1; else b = mid; }
  int hi = a;
  int t = threadIdx.x, c = t & 31, r = t >> 5;
  float s = 0.f;
  for (int n = lo + r; n < hi; n += 8) s += out2[n*32 + c];
  __shared__ float sh[256];
  sh[t] = s; __syncthreads();
  if (r == 0){
    for (int q = 1; q < 8; q++) s += sh[q*32 + c];
    int cg = hi - lo; if (cg < 1) cg = 1;
    gpool[g*32 + c] = s / (float)cg;
  }
}

// ---- MLP head ------------------------------------------------------------
__global__ __launch_bounds__(1024) void k_mlp(const float* __restrict__ gpool, const float* __restrict__ W3,
    const float* __restrict__ b3, const float* __restrict__ W4, const float* __restrict__ b4,
    float* __restrict__ out){
  __shared__ float z[64*16];
  int t = threadIdx.x;
  {
    int g = t >> 4, jj = t & 15;
    float s = b3[jj];
    #pragma unroll
    for (int c = 0; c < 32; c++) s = fmaf(gpool[g*32 + c], W3[c*16 + jj], s);
    z[t] = fmaxf(s, 0.f);
  }
  __syncthreads();
  if (t < 640){
    int g = t / 10, o = t - g*10;
    float s = b4[o];
    #pragma unroll
    for (int jj = 0; jj < 16; jj++) s = fmaf(z[g*16 + jj], W4[jj*10 + o], s);
    out[t] = s;
  }
}

extern "C" void kernel_launch(void* const* d_in, const int* in_sizes, int n_in,
                              void* d_out, int out_size, void* d_ws, size_t ws_size,
                              hipStream_t stream) {
  (void)in_sizes; (void)n_in; (void)out_size; (void)ws_size;
  const float* x     = (const float*)d_in[0];
  const int*   ei    = (const int*)  d_in[1];
  const float* eattr = (const float*)d_in[2];
  const int*   batch = (const int*)  d_in[3];
  const float* W1    = (const float*)d_in[4];
  const float* as1   = (const float*)d_in[5];
  const float* ad1   = (const float*)d_in[6];
  const float* We1   = (const float*)d_in[7];
  const float* ae1w  = (const float*)d_in[8];
  const float* b1    = (const float*)d_in[9];
  const float* W2    = (const float*)d_in[10];
  const float* as2   = (const float*)d_in[11];
  const float* ad2   = (const float*)d_in[12];
  const float* We2   = (const float*)d_in[13];
  const float* ae2w  = (const float*)d_in[14];
  const float* b2    = (const float*)d_in[15];
  const float* W3    = (const float*)d_in[16];
  const float* b3    = (const float*)d_in[17];
  const float* W4    = (const float*)d_in[18];
  const float* b4    = (const float*)d_in[19];
  float* out = (float*)d_out;
  const int* src  = ei;
  const int* dstp = ei + N_EDGES;

  char* p = (char*)d_ws;
  auto alloc = [&](size_t bytes)->void*{ void* r = (void*)p; p += (bytes + 255) & ~(size_t)255; return r; };
  int*   cnt      = (int*)  alloc(4*N_NODES);
  size_t zero_bytes = (size_t)(p - (char*)d_ws);   // only cnt needs zeroing
  int*   wofs     = (int*)  alloc(4*N_NODES);
  int*   rowptr   = (int*)  alloc(4*(N_NODES+1));
  int*   bsum     = (int*)  alloc(4*NB);
  int*   bpre     = (int*)  alloc(4*NB);
  int2*  s_pack   = (int2*) alloc(8*N_EDGES);
  float* vbuf     = (float*)alloc(4*40);
  float* ae1      = (float*)alloc(16*N_EDGES);
  float* ae2      = (float*)alloc(4*N_EDGES);
  float* h1       = (float*)alloc(4*N_NODES*HC);
  float* als1     = (float*)alloc(16*N_NODES);
  float* ald1     = (float*)alloc(16*N_NODES);
  float* h_elu    = (float*)alloc(4*N_NODES*HC);
  float* h2       = (float*)alloc(4*N_NODES*HID);
  float* als2     = (float*)alloc(4*N_NODES);
  float* ald2     = (float*)alloc(4*N_NODES);
  float* out2     = (float*)alloc(4*N_NODES*HID);
  float* gpool    = (float*)alloc(4*N_GRAPHS*HID);

  const int EB = (N_EDGES + 255)/256;   // 3125

  hipMemsetAsync(d_ws, 0, zero_bytes, stream);
  k_v      <<<1,    64,  0, stream>>>(We1, ae1w, We2, ae2w, vbuf);
  k_hist   <<<EB,   256, 0, stream>>>(dstp, cnt);
  k_blocksum<<<NB,  256, 0, stream>>>(cnt, bsum);
  k_scanb  <<<1,    256, 0, stream>>>(bsum, bpre);
  k_rowptr <<<NB,   256, 0, stream>>>(cnt, bpre, rowptr, wofs);
  k_scatter<<<EB,   256, 0, stream>>>(src, dstp, eattr, vbuf, wofs, s_pack, ae1, ae2);
  k_gemm1  <<<(N_NODES+63)/64, 256, 0, stream>>>(x, W1, as1, ad1, h1, als1, ald1);
  k_conv1  <<<(N_NODES+3)/4,   256, 0, stream>>>(rowptr, s_pack, als1, ald1, ae1, h1, b1, h_elu);
  k_gemm2  <<<(N_NODES+15)/16, 256, 0, stream>>>(h_elu, W2, as2, ad2, h2, als2, ald2);
  k_conv2  <<<(N_NODES+3)/4,   256, 0, stream>>>(rowptr, s_pack, als2, ald2, ae2, h2, b2, out2);
  k_pool   <<<N_GRAPHS, 256, 0, stream>>>(out2, batch, gpool);
  k_mlp    <<<1,   1024, 0, stream>>>(gpool, W3, b3, W4, b4, out);
}

// Round 4
// 461.326 us; speedup vs baseline: 2.4894x; 1.0055x over previous
//
#include <hip/hip_runtime.h>
#include <hip/hip_bf16.h>
#include <math.h>

#define N_NODES 50000
#define N_EDGES 800000
#define N_GRAPHS 64
#define IN_DIM 128
#define HID 32
#define HEADS 4
#define EDGE_DIM 8
#define OUT_DIM 10
#define HC 128          // HEADS*HID
#define NB 196          // ceil(N_NODES/256)

__device__ __forceinline__ float leaky(float x){ return x >= 0.f ? x : 0.2f*x; }
__device__ __forceinline__ float elu_f(float x){ return x > 0.f ? x : __expf(x)-1.f; }

// ---- degree histogram: ONE int atomic per edge ---------------------------
__global__ __launch_bounds__(256) void k_hist(const int* __restrict__ dst, int* __restrict__ cnt){
  int e = blockIdx.x*256 + threadIdx.x;
  if (e >= N_EDGES) return;
  atomicAdd(&cnt[dst[e]], 1);
}

__global__ __launch_bounds__(256) void k_blocksum(const int* __restrict__ cnt, int* __restrict__ bsum){
  __shared__ int sh[256];
  int n = blockIdx.x*256 + threadIdx.x;
  sh[threadIdx.x] = (n < N_NODES) ? cnt[n] : 0;
  __syncthreads();
  for (int off = 128; off > 0; off >>= 1){
    if (threadIdx.x < off) sh[threadIdx.x] += sh[threadIdx.x + off];
    __syncthreads();
  }
  if (threadIdx.x == 0) bsum[blockIdx.x] = sh[0];
}

__global__ __launch_bounds__(256) void k_scanb(const int* __restrict__ bsum, int* __restrict__ bpre){
  __shared__ int sh[256];
  int t = threadIdx.x;
  int v = (t < NB) ? bsum[t] : 0;
  sh[t] = v; __syncthreads();
  for (int off = 1; off < 256; off <<= 1){
    int u = (t >= off) ? sh[t-off] : 0;
    __syncthreads();
    sh[t] += u;
    __syncthreads();
  }
  if (t < NB) bpre[t] = sh[t] - v;
}

__global__ __launch_bounds__(256) void k_rowptr(const int* __restrict__ cnt, const int* __restrict__ bpre,
    int* __restrict__ rowptr, int* __restrict__ wofs){
  __shared__ int sh[256];
  int t = threadIdx.x; int n = blockIdx.x*256 + t;
  int c = (n < N_NODES) ? cnt[n] : 0;
  sh[t] = c; __syncthreads();
  for (int off = 1; off < 256; off <<= 1){
    int u = (t >= off) ? sh[t-off] : 0;
    __syncthreads();
    sh[t] += u;
    __syncthreads();
  }
  int incl = sh[t];
  if (n < N_NODES){
    int rp = bpre[blockIdx.x] + incl - c;
    rowptr[n] = rp;
    wofs[n] = rp;
  }
  if (n == N_NODES-1) rowptr[N_NODES] = bpre[blockIdx.x] + incl;
}

// v1[d][h] = sum_c We1[d,h*32+c]*att_e1[h,c]  (32 floats), v2[d] (8 floats)
__global__ void k_v(const float* __restrict__ We1, const float* __restrict__ ae1w,
                    const float* __restrict__ We2, const float* __restrict__ ae2w,
                    float* __restrict__ vbuf){
  int t = threadIdx.x;
  if (t < 32){
    int d = t >> 2, h = t & 3;
    float s = 0.f;
    for (int c = 0; c < 32; c++) s = fmaf(We1[d*128 + h*32 + c], ae1w[h*32 + c], s);
    vbuf[d*4 + h] = s;
  } else if (t < 40){
    int d = t - 32;
    float s = 0.f;
    for (int c = 0; c < 32; c++) s = fmaf(We2[d*32 + c], ae2w[c], s);
    vbuf[32 + d] = s;
  }
}

// ---- GEMM1: h1 = x@W1 [N,128], + al_s1/al_d1 -----------------------------
__global__ __launch_bounds__(256) void k_gemm1(const float* __restrict__ x, const float* __restrict__ W1,
    const float* __restrict__ as1, const float* __restrict__ ad1,
    float* __restrict__ h1, float* __restrict__ als1, float* __restrict__ ald1){
  __shared__ float xs[64][128];  // 32 KB
  __shared__ float ws[64*128];   // 32 KB (one 64-row K-chunk of W1)
  int t = threadIdx.x;
  int cg = t & 15;               // col group: cols c8..c8+7
  int c8 = cg * 8;
  int qb = (t >> 4) * 4;         // node sub-base
  int base = blockIdx.x * 64;
  for (int i = t; i < 2048; i += 256){
    int node = base + (i >> 5);
    int col = (i & 31) * 4;
    float4 v = make_float4(0,0,0,0);
    if (node < N_NODES) v = *(const float4*)&x[node*IN_DIM + col];
    *(float4*)&xs[i>>5][col] = v;
  }
  float acc[4][8];
  #pragma unroll
  for (int q = 0; q < 4; q++)
    #pragma unroll
    for (int i = 0; i < 8; i++) acc[q][i] = 0.f;

  for (int kb = 0; kb < 128; kb += 64){
    __syncthreads();
    for (int i = t; i < 2048; i += 256)
      *(float4*)&ws[i*4] = *(const float4*)&W1[kb*128 + i*4];
    __syncthreads();
    #pragma unroll 4
    for (int k = 0; k < 64; k++){
      float4 w0 = *(float4*)&ws[k*128 + c8];
      float4 w1 = *(float4*)&ws[k*128 + c8 + 4];
      #pragma unroll
      for (int q = 0; q < 4; q++){
        float xv = xs[qb + q][kb + k];
        acc[q][0] = fmaf(xv, w0.x, acc[q][0]);
        acc[q][1] = fmaf(xv, w0.y, acc[q][1]);
        acc[q][2] = fmaf(xv, w0.z, acc[q][2]);
        acc[q][3] = fmaf(xv, w0.w, acc[q][3]);
        acc[q][4] = fmaf(xv, w1.x, acc[q][4]);
        acc[q][5] = fmaf(xv, w1.y, acc[q][5]);
        acc[q][6] = fmaf(xv, w1.z, acc[q][6]);
        acc[q][7] = fmaf(xv, w1.w, acc[q][7]);
      }
    }
  }
  int head = cg >> 2;
  float asv[8], adv[8];
  #pragma unroll
  for (int i = 0; i < 8; i++){ asv[i] = as1[c8 + i]; adv[i] = ad1[c8 + i]; }
  #pragma unroll
  for (int q = 0; q < 4; q++){
    int n = base + qb + q;
    if (n >= N_NODES) continue;
    float sa = 0.f, sd = 0.f;
    #pragma unroll
    for (int i = 0; i < 8; i++){
      sa = fmaf(acc[q][i], asv[i], sa);
      sd = fmaf(acc[q][i], adv[i], sd);
    }
    sa += __shfl_xor(sa, 1); sd += __shfl_xor(sd, 1);
    sa += __shfl_xor(sa, 2); sd += __shfl_xor(sd, 2);
    *(float4*)&h1[n*HC + c8]     = make_float4(acc[q][0], acc[q][1], acc[q][2], acc[q][3]);
    *(float4*)&h1[n*HC + c8 + 4] = make_float4(acc[q][4], acc[q][5], acc[q][6], acc[q][7]);
    if ((cg & 3) == 0){ als1[n*4 + head] = sa; ald1[n*4 + head] = sd; }
  }
}

// ---- scatter: CSR fill + full layer-1 attention coefficient --------------
// exp WITHOUT max-shift: alpha ~ N(0,1), |alpha|max ~ 5 over 3.2M samples,
// exp <= ~150, den <= ~degree*150 -> safe in fp32; softmax identical.
__global__ __launch_bounds__(256) void k_scatter(const int* __restrict__ src, const int* __restrict__ dst,
    const float* __restrict__ eattr, const float* __restrict__ vbuf,
    const float* __restrict__ als1, const float* __restrict__ ald1,
    int* __restrict__ wofs, int* __restrict__ rec_src,
    float4* __restrict__ rec_p1, float4* __restrict__ rec_ae1, float* __restrict__ rec_ae2){
  __shared__ float v[40];
  if (threadIdx.x < 40) v[threadIdx.x] = vbuf[threadIdx.x];
  __syncthreads();
  int e = blockIdx.x*256 + threadIdx.x;
  if (e >= N_EDGES) return;
  int s = src[e], d = dst[e];
  float4 x0 = *(const float4*)&eattr[e*8];
  float4 x1 = *(const float4*)&eattr[e*8+4];
  float ea[8] = {x0.x,x0.y,x0.z,x0.w,x1.x,x1.y,x1.z,x1.w};
  float4 r = make_float4(0,0,0,0);
  float r2 = 0.f;
  #pragma unroll
  for (int dd = 0; dd < 8; dd++){
    r.x = fmaf(ea[dd], v[dd*4+0], r.x);
    r.y = fmaf(ea[dd], v[dd*4+1], r.y);
    r.z = fmaf(ea[dd], v[dd*4+2], r.z);
    r.w = fmaf(ea[dd], v[dd*4+3], r.w);
    r2  = fmaf(ea[dd], v[32+dd], r2);
  }
  float4 as = *(const float4*)&als1[s*4];
  float4 ad = *(const float4*)&ald1[d*4];
  float4 p;
  p.x = __expf(leaky(as.x + ad.x + r.x));
  p.y = __expf(leaky(as.y + ad.y + r.y));
  p.z = __expf(leaky(as.z + ad.z + r.z));
  p.w = __expf(leaky(as.w + ad.w + r.w));
  int pos = atomicAdd(&wofs[d], 1);
  rec_src[pos] = s;
  rec_p1[pos]  = p;
  rec_ae1[pos] = r;
  rec_ae2[pos] = r2;
}

// ---- per-node self-loop coefficient, layer 1 -----------------------------
__global__ __launch_bounds__(256) void k_self1(const int* __restrict__ rowptr,
    const float4* __restrict__ rec_ae1, const float* __restrict__ als1, const float* __restrict__ ald1,
    float* __restrict__ pself1){
  int n = blockIdx.x*256 + threadIdx.x;
  if (n >= N_NODES) return;
  int r0 = rowptr[n], r1 = rowptr[n+1];
  float4 s = make_float4(0,0,0,0);
  for (int k = r0; k < r1; k++){
    float4 a = rec_ae1[k];
    s.x += a.x; s.y += a.y; s.z += a.z; s.w += a.w;
  }
  int cn = r1 - r0; if (cn < 1) cn = 1;
  float inv = 1.f / (float)cn;
  float4 as = *(const float4*)&als1[n*4];
  float4 ad = *(const float4*)&ald1[n*4];
  float4 p;
  p.x = __expf(leaky(as.x + ad.x + s.x*inv));
  p.y = __expf(leaky(as.y + ad.y + s.y*inv));
  p.z = __expf(leaky(as.z + ad.z + s.z*inv));
  p.w = __expf(leaky(as.w + ad.w + s.w*inv));
  *(float4*)&pself1[n*4] = p;
}

// ---- conv1 aggregation: one wave per node, precomputed coefficients ------
__global__ __launch_bounds__(256) void k_conv1(const int* __restrict__ rowptr, const int* __restrict__ rec_src,
    const float* __restrict__ rec_p1f, const float* __restrict__ pself1,
    const float* __restrict__ h1, const float* __restrict__ b1, float* __restrict__ h_elu){
  int wv = threadIdx.x >> 6, l = threadIdx.x & 63;
  int n = blockIdx.x*4 + wv;
  if (n >= N_NODES) return;
  int c0 = l*2, h = l >> 4;
  float ps = pself1[n*4 + h];
  float2 hs = *(const float2*)&h1[n*HC + c0];
  float den = ps;
  float2 acc = make_float2(ps*hs.x, ps*hs.y);
  int r0 = rowptr[n], r1 = rowptr[n+1];
  int k = r0;
  for (; k + 2 <= r1; k += 2){
    int s0 = rec_src[k], s1 = rec_src[k+1];
    float p0 = rec_p1f[k*4 + h], p1 = rec_p1f[(k+1)*4 + h];
    float2 a0 = *(const float2*)&h1[s0*HC + c0];
    float2 a1 = *(const float2*)&h1[s1*HC + c0];
    den += p0 + p1;
    acc.x = fmaf(p0, a0.x, acc.x); acc.y = fmaf(p0, a0.y, acc.y);
    acc.x = fmaf(p1, a1.x, acc.x); acc.y = fmaf(p1, a1.y, acc.y);
  }
  if (k < r1){
    int s0 = rec_src[k];
    float p0 = rec_p1f[k*4 + h];
    float2 a0 = *(const float2*)&h1[s0*HC + c0];
    den += p0;
    acc.x = fmaf(p0, a0.x, acc.x); acc.y = fmaf(p0, a0.y, acc.y);
  }
  float inv = 1.f / (den + 1e-16f);
  float o0 = fmaf(acc.x, inv, b1[c0]);
  float o1 = fmaf(acc.y, inv, b1[c0+1]);
  *(float2*)&h_elu[n*HC + c0] = make_float2(elu_f(o0), elu_f(o1));
}

// ---- GEMM2: h2 = h_elu@W2 [N,32], + al_s2/al_d2 --------------------------
__global__ __launch_bounds__(256) void k_gemm2(const float* __restrict__ hin, const float* __restrict__ W2,
    const float* __restrict__ as2, const float* __restrict__ ad2,
    float* __restrict__ h2, float* __restrict__ als2, float* __restrict__ ald2){
  __shared__ float ws[128*32];   // 16 KB full W2
  __shared__ float xs[16][128];  // 8 KB
  int t = threadIdx.x; int c = t & 31; int j = t >> 5;  // j: 0..7
  int base = blockIdx.x * 16;
  for (int i = t; i < 1024; i += 256)
    *(float4*)&ws[i*4] = *(const float4*)&W2[i*4];
  for (int i = t; i < 512; i += 256){
    int node = base + (i >> 5);
    int col = (i & 31) * 4;
    float4 v = make_float4(0,0,0,0);
    if (node < N_NODES) v = *(const float4*)&hin[node*128 + col];
    *(float4*)&xs[i>>5][col] = v;
  }
  __syncthreads();
  float s0 = 0.f, s1 = 0.f;
  #pragma unroll 8
  for (int k = 0; k < 128; k++){
    float w = ws[k*32 + c];
    s0 = fmaf(xs[j*2][k],   w, s0);
    s1 = fmaf(xs[j*2+1][k], w, s1);
  }
  float a2c = as2[c], d2c = ad2[c];
  int n0 = base + j*2, n1 = n0 + 1;
  float sa0 = s0*a2c, sd0 = s0*d2c, sa1 = s1*a2c, sd1 = s1*d2c;
  #pragma unroll
  for (int off = 1; off < 32; off <<= 1){
    sa0 += __shfl_xor(sa0, off); sd0 += __shfl_xor(sd0, off);
    sa1 += __shfl_xor(sa1, off); sd1 += __shfl_xor(sd1, off);
  }
  if (n0 < N_NODES){ h2[n0*32 + c] = s0; if (c == 0){ als2[n0] = sa0; ald2[n0] = sd0; } }
  if (n1 < N_NODES){ h2[n1*32 + c] = s1; if (c == 0){ als2[n1] = sa1; ald2[n1] = sd1; } }
}

// ---- per-edge + self coefficients, layer 2 -------------------------------
__global__ __launch_bounds__(256) void k_alpha2(const int* __restrict__ rowptr, const int* __restrict__ rec_src,
    const float* __restrict__ rec_ae2, const float* __restrict__ als2, const float* __restrict__ ald2,
    float* __restrict__ rec_p2, float* __restrict__ pself2){
  int n = blockIdx.x*256 + threadIdx.x;
  if (n >= N_NODES) return;
  int r0 = rowptr[n], r1 = rowptr[n+1];
  float adn = ald2[n];
  float sum2 = 0.f;
  for (int k = r0; k < r1; k++){
    float ae = rec_ae2[k];
    sum2 += ae;
    rec_p2[k] = __expf(leaky(als2[rec_src[k]] + adn + ae));
  }
  int cn = r1 - r0; if (cn < 1) cn = 1;
  pself2[n] = __expf(leaky(als2[n] + adn + sum2 / (float)cn));
}

// ---- conv2 aggregation: one wave per node, half-wave edge split ----------
__global__ __launch_bounds__(256) void k_conv2(const int* __restrict__ rowptr, const int* __restrict__ rec_src,
    const float* __restrict__ rec_p2, const float* __restrict__ pself2,
    const float* __restrict__ h2, const float* __restrict__ b2, float* __restrict__ out2){
  int wv = threadIdx.x >> 6, l = threadIdx.x & 63;
  int n = blockIdx.x*4 + wv;
  if (n >= N_NODES) return;
  int half = l >> 5, c = l & 31;
  int r0 = rowptr[n], r1 = rowptr[n+1];
  int h0 = (r1 - r0 + 1) >> 1;
  int ks = half ? r0 + h0 : r0;
  int ke = half ? r1 : r0 + h0;
  float den = 0.f, acc = 0.f;
  if (half == 0){
    float ps = pself2[n];
    den = ps;
    acc = ps * h2[n*32 + c];
  }
  for (int k = ks; k < ke; k++){
    int s = rec_src[k];
    float p = rec_p2[k];
    float hv = h2[s*32 + c];
    den += p;
    acc = fmaf(p, hv, acc);
  }
  den += __shfl_xor(den, 32);
  acc += __shfl_xor(acc, 32);
  float val = acc / (den + 1e-16f) + b2[c];
  if (half == 0) out2[n*32 + c] = elu_f(val);
}

// ---- global mean pool (batch is sorted) ----------------------------------
__global__ __launch_bounds__(256) void k_pool(const float* __restrict__ out2, const int* __restrict__ batch,
    float* __restrict__ gpool){
  int g = blockIdx.x;
  int a = 0, b = N_NODES;
  while (a < b){ int mid = (a + b) >> 1; if (batch[mid] < g) a = mid + 1; else b = mid; }
  int lo = a;
  a = lo; b = N_NODES;
  while (a < b){ int mid = (a + b) >> 1; if (batch[mid] < g + 1) a = mid + 1; else b = mid; }
  int hi = a;
  int t = threadIdx.x, c = t & 31, r = t >> 5;
  float s = 0.f;
  for (int n = lo + r; n < hi; n += 8) s += out2[n*32 + c];
  __shared__ float sh[256];
  sh[t] = s; __syncthreads();
  if (r == 0){
    for (int q = 1; q < 8; q++) s += sh[q*32 + c];
    int cg = hi - lo; if (cg < 1) cg = 1;
    gpool[g*32 + c] = s / (float)cg;
  }
}

// ---- MLP head ------------------------------------------------------------
__global__ __launch_bounds__(1024) void k_mlp(const float* __restrict__ gpool, const float* __restrict__ W3,
    const float* __restrict__ b3, const float* __restrict__ W4, const float* __restrict__ b4,
    float* __restrict__ out){
  __shared__ float z[64*16];
  int t = threadIdx.x;
  {
    int g = t >> 4, jj = t & 15;
    float s = b3[jj];
    #pragma unroll
    for (int c = 0; c < 32; c++) s = fmaf(gpool[g*32 + c], W3[c*16 + jj], s);
    z[t] = fmaxf(s, 0.f);
  }
  __syncthreads();
  if (t < 640){
    int g = t / 10, o = t - g*10;
    float s = b4[o];
    #pragma unroll
    for (int jj = 0; jj < 16; jj++) s = fmaf(z[g*16 + jj], W4[jj*10 + o], s);
    out[t] = s;
  }
}

extern "C" void kernel_launch(void* const* d_in, const int* in_sizes, int n_in,
                              void* d_out, int out_size, void* d_ws, size_t ws_size,
                              hipStream_t stream) {
  (void)in_sizes; (void)n_in; (void)out_size; (void)ws_size;
  const float* x     = (const float*)d_in[0];
  const int*   ei    = (const int*)  d_in[1];
  const float* eattr = (const float*)d_in[2];
  const int*   batch = (const int*)  d_in[3];
  const float* W1    = (const float*)d_in[4];
  const float* as1   = (const float*)d_in[5];
  const float* ad1   = (const float*)d_in[6];
  const float* We1   = (const float*)d_in[7];
  const float* ae1w  = (const float*)d_in[8];
  const float* b1    = (const float*)d_in[9];
  const float* W2    = (const float*)d_in[10];
  const float* as2   = (const float*)d_in[11];
  const float* ad2   = (const float*)d_in[12];
  const float* We2   = (const float*)d_in[13];
  const float* ae2w  = (const float*)d_in[14];
  const float* b2    = (const float*)d_in[15];
  const float* W3    = (const float*)d_in[16];
  const float* b3    = (const float*)d_in[17];
  const float* W4    = (const float*)d_in[18];
  const float* b4    = (const float*)d_in[19];
  float* out = (float*)d_out;
  const int* src  = ei;
  const int* dstp = ei + N_EDGES;

  char* p = (char*)d_ws;
  auto alloc = [&](size_t bytes)->void*{ void* r = (void*)p; p += (bytes + 255) & ~(size_t)255; return r; };
  int*    cnt      = (int*)   alloc(4*N_NODES);
  size_t  zero_bytes = (size_t)(p - (char*)d_ws);   // only cnt needs zeroing
  int*    wofs     = (int*)   alloc(4*N_NODES);
  int*    rowptr   = (int*)   alloc(4*(N_NODES+1));
  int*    bsum     = (int*)   alloc(4*NB);
  int*    bpre     = (int*)   alloc(4*NB);
  int*    rec_src  = (int*)   alloc(4*N_EDGES);
  float4* rec_p1   = (float4*)alloc(16*N_EDGES);
  float4* rec_ae1  = (float4*)alloc(16*N_EDGES);
  float*  rec_ae2  = (float*) alloc(4*N_EDGES);
  float*  rec_p2   = (float*) alloc(4*N_EDGES);
  float*  vbuf     = (float*) alloc(4*40);
  float*  pself1   = (float*) alloc(16*N_NODES);
  float*  pself2   = (float*) alloc(4*N_NODES);
  float*  h1       = (float*) alloc(4*N_NODES*HC);
  float*  als1     = (float*) alloc(16*N_NODES);
  float*  ald1     = (float*) alloc(16*N_NODES);
  float*  h_elu    = (float*) alloc(4*N_NODES*HC);
  float*  h2       = (float*) alloc(4*N_NODES*HID);
  float*  als2     = (float*) alloc(4*N_NODES);
  float*  ald2     = (float*) alloc(4*N_NODES);
  float*  out2     = (float*) alloc(4*N_NODES*HID);
  float*  gpool    = (float*) alloc(4*N_GRAPHS*HID);

  const int EB = (N_EDGES + 255)/256;   // 3125

  hipMemsetAsync(d_ws, 0, zero_bytes, stream);
  k_v       <<<1,    64,  0, stream>>>(We1, ae1w, We2, ae2w, vbuf);
  k_hist    <<<EB,   256, 0, stream>>>(dstp, cnt);
  k_blocksum<<<NB,   256, 0, stream>>>(cnt, bsum);
  k_scanb   <<<1,    256, 0, stream>>>(bsum, bpre);
  k_rowptr  <<<NB,   256, 0, stream>>>(cnt, bpre, rowptr, wofs);
  k_gemm1   <<<(N_NODES+63)/64, 256, 0, stream>>>(x, W1, as1, ad1, h1, als1, ald1);
  k_scatter <<<EB,   256, 0, stream>>>(src, dstp, eattr, vbuf, als1, ald1,
                                       wofs, rec_src, rec_p1, rec_ae1, rec_ae2);
  k_self1   <<<NB,   256, 0, stream>>>(rowptr, rec_ae1, als1, ald1, pself1);
  k_conv1   <<<(N_NODES+3)/4, 256, 0, stream>>>(rowptr, rec_src, (const float*)rec_p1, pself1, h1, b1, h_elu);
  k_gemm2   <<<(N_NODES+15)/16, 256, 0, stream>>>(h_elu, W2, as2, ad2, h2, als2, ald2);
  k_alpha2  <<<NB,   256, 0, stream>>>(rowptr, rec_src, rec_ae2, als2, ald2, rec_p2, pself2);
  k_conv2   <<<(N_NODES+3)/4, 256, 0, stream>>>(rowptr, rec_src, rec_p2, pself2, h2, b2, out2);
  k_pool    <<<N_GRAPHS, 256, 0, stream>>>(out2, batch, gpool);
  k_mlp     <<<1,   1024, 0, stream>>>(gpool, W3, b3, W4, b4, out);
}

// Round 5
// 438.362 us; speedup vs baseline: 2.6198x; 1.0524x over previous
//
#include <hip/hip_runtime.h>
#include <hip/hip_bf16.h>
#include <math.h>

#define N_NODES 50000
#define N_EDGES 800000
#define N_GRAPHS 64
#define IN_DIM 128
#define HID 32
#define HEADS 4
#define EDGE_DIM 8
#define OUT_DIM 10
#define HC 128          // HEADS*HID
#define NB 196          // ceil(N_NODES/256)

__device__ __forceinline__ float leaky(float x){ return x >= 0.f ? x : 0.2f*x; }
__device__ __forceinline__ float elu_f(float x){ return x > 0.f ? x : __expf(x)-1.f; }

// v1[d][h] = sum_c We1[d,h*32+c]*att_e1[h,c]  (32 floats), v2[d] (8 floats)
__global__ void k_v(const float* __restrict__ We1, const float* __restrict__ ae1w,
                    const float* __restrict__ We2, const float* __restrict__ ae2w,
                    float* __restrict__ vbuf){
  int t = threadIdx.x;
  if (t < 32){
    int d = t >> 2, h = t & 3;
    float s = 0.f;
    for (int c = 0; c < 32; c++) s = fmaf(We1[d*128 + h*32 + c], ae1w[h*32 + c], s);
    vbuf[d*4 + h] = s;
  } else if (t < 40){
    int d = t - 32;
    float s = 0.f;
    for (int c = 0; c < 32; c++) s = fmaf(We2[d*32 + c], ae2w[c], s);
    vbuf[32 + d] = s;
  }
}

// ---- histogram + edge-order attention scalars (all coalesced) ------------
__global__ __launch_bounds__(256) void k_histae(const int* __restrict__ dst,
    const float* __restrict__ eattr, const float* __restrict__ vbuf,
    int* __restrict__ cnt, float* __restrict__ ae1, float* __restrict__ ae2){
  __shared__ float v[40];
  if (threadIdx.x < 40) v[threadIdx.x] = vbuf[threadIdx.x];
  __syncthreads();
  int e = blockIdx.x*256 + threadIdx.x;
  if (e >= N_EDGES) return;
  atomicAdd(&cnt[dst[e]], 1);
  float4 x0 = *(const float4*)&eattr[e*8];
  float4 x1 = *(const float4*)&eattr[e*8+4];
  float ea[8] = {x0.x,x0.y,x0.z,x0.w,x1.x,x1.y,x1.z,x1.w};
  float4 r = make_float4(0,0,0,0);
  float r2 = 0.f;
  #pragma unroll
  for (int dd = 0; dd < 8; dd++){
    r.x = fmaf(ea[dd], v[dd*4+0], r.x);
    r.y = fmaf(ea[dd], v[dd*4+1], r.y);
    r.z = fmaf(ea[dd], v[dd*4+2], r.z);
    r.w = fmaf(ea[dd], v[dd*4+3], r.w);
    r2  = fmaf(ea[dd], v[32+dd], r2);
  }
  *(float4*)&ae1[e*4] = r;
  ae2[e] = r2;
}

__global__ __launch_bounds__(256) void k_blocksum(const int* __restrict__ cnt, int* __restrict__ bsum){
  __shared__ int sh[256];
  int n = blockIdx.x*256 + threadIdx.x;
  sh[threadIdx.x] = (n < N_NODES) ? cnt[n] : 0;
  __syncthreads();
  for (int off = 128; off > 0; off >>= 1){
    if (threadIdx.x < off) sh[threadIdx.x] += sh[threadIdx.x + off];
    __syncthreads();
  }
  if (threadIdx.x == 0) bsum[blockIdx.x] = sh[0];
}

__global__ __launch_bounds__(256) void k_scanb(const int* __restrict__ bsum, int* __restrict__ bpre){
  __shared__ int sh[256];
  int t = threadIdx.x;
  int v = (t < NB) ? bsum[t] : 0;
  sh[t] = v; __syncthreads();
  for (int off = 1; off < 256; off <<= 1){
    int u = (t >= off) ? sh[t-off] : 0;
    __syncthreads();
    sh[t] += u;
    __syncthreads();
  }
  if (t < NB) bpre[t] = sh[t] - v;
}

__global__ __launch_bounds__(256) void k_rowptr(const int* __restrict__ cnt, const int* __restrict__ bpre,
    int* __restrict__ rowptr, int* __restrict__ wofs){
  __shared__ int sh[256];
  int t = threadIdx.x; int n = blockIdx.x*256 + t;
  int c = (n < N_NODES) ? cnt[n] : 0;
  sh[t] = c; __syncthreads();
  for (int off = 1; off < 256; off <<= 1){
    int u = (t >= off) ? sh[t-off] : 0;
    __syncthreads();
    sh[t] += u;
    __syncthreads();
  }
  int incl = sh[t];
  if (n < N_NODES){
    int rp = bpre[blockIdx.x] + incl - c;
    rowptr[n] = rp;
    wofs[n] = rp;
  }
  if (n == N_NODES-1) rowptr[N_NODES] = bpre[blockIdx.x] + incl;
}

// ---- CSR fill: ONLY 8 B/edge permuted (6.4 MB region -> L2-resident lines;
// previous 40 B/edge across 32 MB thrashed L2: 127 MB writes, 81 us) -------
__global__ __launch_bounds__(256) void k_scatter(const int* __restrict__ src, const int* __restrict__ dst,
    int* __restrict__ wofs, int2* __restrict__ rec){
  int e = blockIdx.x*256 + threadIdx.x;
  if (e >= N_EDGES) return;
  int d = dst[e];
  int pos = atomicAdd(&wofs[d], 1);
  rec[pos] = make_int2(src[e], e);
}

// ---- GEMM1: h1 = x@W1 [N,128], + al_s1/al_d1 -----------------------------
__global__ __launch_bounds__(256) void k_gemm1(const float* __restrict__ x, const float* __restrict__ W1,
    const float* __restrict__ as1, const float* __restrict__ ad1,
    float* __restrict__ h1, float* __restrict__ als1, float* __restrict__ ald1){
  __shared__ float xs[64][128];  // 32 KB
  __shared__ float ws[64*128];   // 32 KB (one 64-row K-chunk of W1)
  int t = threadIdx.x;
  int cg = t & 15;               // col group: cols c8..c8+7
  int c8 = cg * 8;
  int qb = (t >> 4) * 4;         // node sub-base
  int base = blockIdx.x * 64;
  for (int i = t; i < 2048; i += 256){
    int node = base + (i >> 5);
    int col = (i & 31) * 4;
    float4 v = make_float4(0,0,0,0);
    if (node < N_NODES) v = *(const float4*)&x[node*IN_DIM + col];
    *(float4*)&xs[i>>5][col] = v;
  }
  float acc[4][8];
  #pragma unroll
  for (int q = 0; q < 4; q++)
    #pragma unroll
    for (int i = 0; i < 8; i++) acc[q][i] = 0.f;

  for (int kb = 0; kb < 128; kb += 64){
    __syncthreads();
    for (int i = t; i < 2048; i += 256)
      *(float4*)&ws[i*4] = *(const float4*)&W1[kb*128 + i*4];
    __syncthreads();
    #pragma unroll 4
    for (int k = 0; k < 64; k++){
      float4 w0 = *(float4*)&ws[k*128 + c8];
      float4 w1 = *(float4*)&ws[k*128 + c8 + 4];
      #pragma unroll
      for (int q = 0; q < 4; q++){
        float xv = xs[qb + q][kb + k];
        acc[q][0] = fmaf(xv, w0.x, acc[q][0]);
        acc[q][1] = fmaf(xv, w0.y, acc[q][1]);
        acc[q][2] = fmaf(xv, w0.z, acc[q][2]);
        acc[q][3] = fmaf(xv, w0.w, acc[q][3]);
        acc[q][4] = fmaf(xv, w1.x, acc[q][4]);
        acc[q][5] = fmaf(xv, w1.y, acc[q][5]);
        acc[q][6] = fmaf(xv, w1.z, acc[q][6]);
        acc[q][7] = fmaf(xv, w1.w, acc[q][7]);
      }
    }
  }
  int head = cg >> 2;
  float asv[8], adv[8];
  #pragma unroll
  for (int i = 0; i < 8; i++){ asv[i] = as1[c8 + i]; adv[i] = ad1[c8 + i]; }
  #pragma unroll
  for (int q = 0; q < 4; q++){
    int n = base + qb + q;
    if (n >= N_NODES) continue;
    float sa = 0.f, sd = 0.f;
    #pragma unroll
    for (int i = 0; i < 8; i++){
      sa = fmaf(acc[q][i], asv[i], sa);
      sd = fmaf(acc[q][i], adv[i], sd);
    }
    sa += __shfl_xor(sa, 1); sd += __shfl_xor(sd, 1);
    sa += __shfl_xor(sa, 2); sd += __shfl_xor(sd, 2);
    *(float4*)&h1[n*HC + c8]     = make_float4(acc[q][0], acc[q][1], acc[q][2], acc[q][3]);
    *(float4*)&h1[n*HC + c8 + 4] = make_float4(acc[q][4], acc[q][5], acc[q][6], acc[q][7]);
    if ((cg & 3) == 0){ als1[n*4 + head] = sa; ald1[n*4 + head] = sd; }
  }
}

// ---- conv1: one wave per node; recompute p=exp(leaky(.)) inline ----------
// (no max-shift: alpha sd~1, |alpha|max ~6 over 3.2M samples -> fp32 safe;
//  exp hides under the 512 B/edge h1-row gather. sum_ae accumulated in-loop
//  so the mean-attr self-loop term folds in at the end.)
__global__ __launch_bounds__(256) void k_conv1(const int* __restrict__ rowptr, const int2* __restrict__ rec,
    const float* __restrict__ als1, const float* __restrict__ ald1, const float* __restrict__ ae1,
    const float* __restrict__ h1, const float* __restrict__ b1, float* __restrict__ h_elu){
  int wv = threadIdx.x >> 6, l = threadIdx.x & 63;
  int n = blockIdx.x*4 + wv;
  if (n >= N_NODES) return;
  int c0 = l*2, h = l >> 4;
  float ad = ald1[n*4 + h];
  float den = 0.f, sum_ae = 0.f;
  float2 acc = make_float2(0.f, 0.f);
  int r0 = rowptr[n], r1 = rowptr[n+1];
  int k = r0;
  for (; k + 2 <= r1; k += 2){
    int2 se0 = rec[k], se1 = rec[k+1];
    float ae_0 = ae1[se0.y*4 + h], ae_1 = ae1[se1.y*4 + h];
    float as_0 = als1[se0.x*4 + h], as_1 = als1[se1.x*4 + h];
    float2 hv0 = *(const float2*)&h1[se0.x*HC + c0];
    float2 hv1 = *(const float2*)&h1[se1.x*HC + c0];
    float p0 = __expf(leaky(as_0 + ad + ae_0));
    float p1 = __expf(leaky(as_1 + ad + ae_1));
    sum_ae += ae_0 + ae_1;
    den += p0 + p1;
    acc.x = fmaf(p0, hv0.x, acc.x); acc.y = fmaf(p0, hv0.y, acc.y);
    acc.x = fmaf(p1, hv1.x, acc.x); acc.y = fmaf(p1, hv1.y, acc.y);
  }
  if (k < r1){
    int2 se = rec[k];
    float aev = ae1[se.y*4 + h];
    float p = __expf(leaky(als1[se.x*4 + h] + ad + aev));
    sum_ae += aev; den += p;
    float2 hv = *(const float2*)&h1[se.x*HC + c0];
    acc.x = fmaf(p, hv.x, acc.x); acc.y = fmaf(p, hv.y, acc.y);
  }
  int cn = r1 - r0; if (cn < 1) cn = 1;
  float ps = __expf(leaky(als1[n*4 + h] + ad + sum_ae / (float)cn));
  float2 hs = *(const float2*)&h1[n*HC + c0];
  den += ps;
  acc.x = fmaf(ps, hs.x, acc.x); acc.y = fmaf(ps, hs.y, acc.y);
  float inv = 1.f / (den + 1e-16f);
  float o0 = fmaf(acc.x, inv, b1[c0]);
  float o1 = fmaf(acc.y, inv, b1[c0+1]);
  *(float2*)&h_elu[n*HC + c0] = make_float2(elu_f(o0), elu_f(o1));
}

// ---- GEMM2: h2 = h_elu@W2 [N,32], + al_s2/al_d2 --------------------------
__global__ __launch_bounds__(256) void k_gemm2(const float* __restrict__ hin, const float* __restrict__ W2,
    const float* __restrict__ as2, const float* __restrict__ ad2,
    float* __restrict__ h2, float* __restrict__ als2, float* __restrict__ ald2){
  __shared__ float ws[128*32];   // 16 KB full W2
  __shared__ float xs[16][128];  // 8 KB
  int t = threadIdx.x; int c = t & 31; int j = t >> 5;  // j: 0..7
  int base = blockIdx.x * 16;
  for (int i = t; i < 1024; i += 256)
    *(float4*)&ws[i*4] = *(const float4*)&W2[i*4];
  for (int i = t; i < 512; i += 256){
    int node = base + (i >> 5);
    int col = (i & 31) * 4;
    float4 v = make_float4(0,0,0,0);
    if (node < N_NODES) v = *(const float4*)&hin[node*128 + col];
    *(float4*)&xs[i>>5][col] = v;
  }
  __syncthreads();
  float s0 = 0.f, s1 = 0.f;
  #pragma unroll 8
  for (int k = 0; k < 128; k++){
    float w = ws[k*32 + c];
    s0 = fmaf(xs[j*2][k],   w, s0);
    s1 = fmaf(xs[j*2+1][k], w, s1);
  }
  float a2c = as2[c], d2c = ad2[c];
  int n0 = base + j*2, n1 = n0 + 1;
  float sa0 = s0*a2c, sd0 = s0*d2c, sa1 = s1*a2c, sd1 = s1*d2c;
  #pragma unroll
  for (int off = 1; off < 32; off <<= 1){
    sa0 += __shfl_xor(sa0, off); sd0 += __shfl_xor(sd0, off);
    sa1 += __shfl_xor(sa1, off); sd1 += __shfl_xor(sd1, off);
  }
  if (n0 < N_NODES){ h2[n0*32 + c] = s0; if (c == 0){ als2[n0] = sa0; ald2[n0] = sd0; } }
  if (n1 < N_NODES){ h2[n1*32 + c] = s1; if (c == 0){ als2[n1] = sa1; ald2[n1] = sd1; } }
}

// ---- conv2: one wave per node, half-wave edge split, inline exp ----------
__global__ __launch_bounds__(256) void k_conv2(const int* __restrict__ rowptr, const int2* __restrict__ rec,
    const float* __restrict__ als2, const float* __restrict__ ald2, const float* __restrict__ ae2,
    const float* __restrict__ h2, const float* __restrict__ b2, float* __restrict__ out2){
  int wv = threadIdx.x >> 6, l = threadIdx.x & 63;
  int n = blockIdx.x*4 + wv;
  if (n >= N_NODES) return;
  int half = l >> 5, c = l & 31;
  float ad = ald2[n];
  int r0 = rowptr[n], r1 = rowptr[n+1];
  int h0 = (r1 - r0 + 1) >> 1;
  int ks = half ? r0 + h0 : r0;
  int ke = half ? r1 : r0 + h0;
  float den = 0.f, acc = 0.f, sum_ae = 0.f;
  for (int k = ks; k < ke; k++){
    int2 se = rec[k];
    float aev = ae2[se.y];
    float p = __expf(leaky(als2[se.x] + ad + aev));
    float hv = h2[se.x*32 + c];
    sum_ae += aev; den += p;
    acc = fmaf(p, hv, acc);
  }
  den += __shfl_xor(den, 32);
  acc += __shfl_xor(acc, 32);
  sum_ae += __shfl_xor(sum_ae, 32);
  int cn = r1 - r0; if (cn < 1) cn = 1;
  float ps = __expf(leaky(als2[n] + ad + sum_ae / (float)cn));
  den += ps;
  acc = fmaf(ps, h2[n*32 + c], acc);
  float val = acc / (den + 1e-16f) + b2[c];
  if (half == 0) out2[n*32 + c] = elu_f(val);
}

// ---- global mean pool (batch is sorted) ----------------------------------
__global__ __launch_bounds__(256) void k_pool(const float* __restrict__ out2, const int* __restrict__ batch,
    float* __restrict__ gpool){
  int g = blockIdx.x;
  int a = 0, b = N_NODES;
  while (a < b){ int mid = (a + b) >> 1; if (batch[mid] < g) a = mid + 1; else b = mid; }
  int lo = a;
  a = lo; b = N_NODES;
  while (a < b){ int mid = (a + b) >> 1; if (batch[mid] < g + 1) a = mid + 1; else b = mid; }
  int hi = a;
  int t = threadIdx.x, c = t & 31, r = t >> 5;
  float s = 0.f;
  for (int n = lo + r; n < hi; n += 8) s += out2[n*32 + c];
  __shared__ float sh[256];
  sh[t] = s; __syncthreads();
  if (r == 0){
    for (int q = 1; q < 8; q++) s += sh[q*32 + c];
    int cg = hi - lo; if (cg < 1) cg = 1;
    gpool[g*32 + c] = s / (float)cg;
  }
}

// ---- MLP head ------------------------------------------------------------
__global__ __launch_bounds__(1024) void k_mlp(const float* __restrict__ gpool, const float* __restrict__ W3,
    const float* __restrict__ b3, const float* __restrict__ W4, const float* __restrict__ b4,
    float* __restrict__ out){
  __shared__ float z[64*16];
  int t = threadIdx.x;
  {
    int g = t >> 4, jj = t & 15;
    float s = b3[jj];
    #pragma unroll
    for (int c = 0; c < 32; c++) s = fmaf(gpool[g*32 + c], W3[c*16 + jj], s);
    z[t] = fmaxf(s, 0.f);
  }
  __syncthreads();
  if (t < 640){
    int g = t / 10, o = t - g*10;
    float s = b4[o];
    #pragma unroll
    for (int jj = 0; jj < 16; jj++) s = fmaf(z[g*16 + jj], W4[jj*10 + o], s);
    out[t] = s;
  }
}

extern "C" void kernel_launch(void* const* d_in, const int* in_sizes, int n_in,
                              void* d_out, int out_size, void* d_ws, size_t ws_size,
                              hipStream_t stream) {
  (void)in_sizes; (void)n_in; (void)out_size; (void)ws_size;
  const float* x     = (const float*)d_in[0];
  const int*   ei    = (const int*)  d_in[1];
  const float* eattr = (const float*)d_in[2];
  const int*   batch = (const int*)  d_in[3];
  const float* W1    = (const float*)d_in[4];
  const float* as1   = (const float*)d_in[5];
  const float* ad1   = (const float*)d_in[6];
  const float* We1   = (const float*)d_in[7];
  const float* ae1w  = (const float*)d_in[8];
  const float* b1    = (const float*)d_in[9];
  const float* W2    = (const float*)d_in[10];
  const float* as2   = (const float*)d_in[11];
  const float* ad2   = (const float*)d_in[12];
  const float* We2   = (const float*)d_in[13];
  const float* ae2w  = (const float*)d_in[14];
  const float* b2    = (const float*)d_in[15];
  const float* W3    = (const float*)d_in[16];
  const float* b3    = (const float*)d_in[17];
  const float* W4    = (const float*)d_in[18];
  const float* b4    = (const float*)d_in[19];
  float* out = (float*)d_out;
  const int* src  = ei;
  const int* dstp = ei + N_EDGES;

  char* p = (char*)d_ws;
  auto alloc = [&](size_t bytes)->void*{ void* r = (void*)p; p += (bytes + 255) & ~(size_t)255; return r; };
  int*    cnt      = (int*)   alloc(4*N_NODES);
  size_t  zero_bytes = (size_t)(p - (char*)d_ws);   // only cnt needs zeroing
  int*    wofs     = (int*)   alloc(4*N_NODES);
  int*    rowptr   = (int*)   alloc(4*(N_NODES+1));
  int*    bsum     = (int*)   alloc(4*NB);
  int*    bpre     = (int*)   alloc(4*NB);
  int2*   rec      = (int2*)  alloc(8*N_EDGES);
  float*  vbuf     = (float*) alloc(4*40);
  float*  ae1      = (float*) alloc(16*N_EDGES);
  float*  ae2      = (float*) alloc(4*N_EDGES);
  float*  h1       = (float*) alloc(4*N_NODES*HC);
  float*  als1     = (float*) alloc(16*N_NODES);
  float*  ald1     = (float*) alloc(16*N_NODES);
  float*  h_elu    = (float*) alloc(4*N_NODES*HC);
  float*  h2       = (float*) alloc(4*N_NODES*HID);
  float*  als2     = (float*) alloc(4*N_NODES);
  float*  ald2     = (float*) alloc(4*N_NODES);
  float*  out2     = (float*) alloc(4*N_NODES*HID);
  float*  gpool    = (float*) alloc(4*N_GRAPHS*HID);

  const int EB = (N_EDGES + 255)/256;   // 3125

  hipMemsetAsync(d_ws, 0, zero_bytes, stream);
  k_v       <<<1,    64,  0, stream>>>(We1, ae1w, We2, ae2w, vbuf);
  k_histae  <<<EB,   256, 0, stream>>>(dstp, eattr, vbuf, cnt, ae1, ae2);
  k_blocksum<<<NB,   256, 0, stream>>>(cnt, bsum);
  k_scanb   <<<1,    256, 0, stream>>>(bsum, bpre);
  k_rowptr  <<<NB,   256, 0, stream>>>(cnt, bpre, rowptr, wofs);
  k_scatter <<<EB,   256, 0, stream>>>(src, dstp, wofs, rec);
  k_gemm1   <<<(N_NODES+63)/64, 256, 0, stream>>>(x, W1, as1, ad1, h1, als1, ald1);
  k_conv1   <<<(N_NODES+3)/4, 256, 0, stream>>>(rowptr, rec, als1, ald1, ae1, h1, b1, h_elu);
  k_gemm2   <<<(N_NODES+15)/16, 256, 0, stream>>>(h_elu, W2, as2, ad2, h2, als2, ald2);
  k_conv2   <<<(N_NODES+3)/4, 256, 0, stream>>>(rowptr, rec, als2, ald2, ae2, h2, b2, out2);
  k_pool    <<<N_GRAPHS, 256, 0, stream>>>(out2, batch, gpool);
  k_mlp     <<<1,   1024, 0, stream>>>(gpool, W3, b3, W4, b4, out);
}

// Round 6
// 404.081 us; speedup vs baseline: 2.8421x; 1.0848x over previous
//
#include <hip/hip_runtime.h>
#include <hip/hip_bf16.h>
#include <math.h>

#define N_NODES 50000
#define N_EDGES 800000
#define N_GRAPHS 64
#define IN_DIM 128
#define HID 32
#define HEADS 4
#define EDGE_DIM 8
#define OUT_DIM 10
#define HC 128          // HEADS*HID
#define NB 196          // ceil(N_NODES/256)

__device__ __forceinline__ float leaky(float x){ return x >= 0.f ? x : 0.2f*x; }
__device__ __forceinline__ float elu_f(float x){ return x > 0.f ? x : __expf(x)-1.f; }

// bf16 helpers (RNE pack; payload-only quantization — attention logits stay fp32)
__device__ __forceinline__ float bf2f(unsigned short u){
  union { unsigned int i; float f; } v; v.i = ((unsigned int)u) << 16; return v.f;
}
__device__ __forceinline__ unsigned short f2bf(float f){
  union { float f; unsigned int i; } v; v.f = f;
  unsigned int r = v.i + 0x7FFF + ((v.i >> 16) & 1);
  return (unsigned short)(r >> 16);
}

// v1[d][h] = sum_c We1[d,h*32+c]*att_e1[h,c]  (32 floats), v2[d] (8 floats)
__global__ void k_v(const float* __restrict__ We1, const float* __restrict__ ae1w,
                    const float* __restrict__ We2, const float* __restrict__ ae2w,
                    float* __restrict__ vbuf){
  int t = threadIdx.x;
  if (t < 32){
    int d = t >> 2, h = t & 3;
    float s = 0.f;
    for (int c = 0; c < 32; c++) s = fmaf(We1[d*128 + h*32 + c], ae1w[h*32 + c], s);
    vbuf[d*4 + h] = s;
  } else if (t < 40){
    int d = t - 32;
    float s = 0.f;
    for (int c = 0; c < 32; c++) s = fmaf(We2[d*32 + c], ae2w[c], s);
    vbuf[32 + d] = s;
  }
}

// ---- histogram + edge-order attention scalars (ae1 packed bf16x4) --------
__global__ __launch_bounds__(256) void k_histae(const int* __restrict__ dst,
    const float* __restrict__ eattr, const float* __restrict__ vbuf,
    int* __restrict__ cnt, unsigned short* __restrict__ ae1h, float* __restrict__ ae2){
  __shared__ float v[40];
  if (threadIdx.x < 40) v[threadIdx.x] = vbuf[threadIdx.x];
  __syncthreads();
  int e = blockIdx.x*256 + threadIdx.x;
  if (e >= N_EDGES) return;
  atomicAdd(&cnt[dst[e]], 1);
  float4 x0 = *(const float4*)&eattr[e*8];
  float4 x1 = *(const float4*)&eattr[e*8+4];
  float ea[8] = {x0.x,x0.y,x0.z,x0.w,x1.x,x1.y,x1.z,x1.w};
  float4 r = make_float4(0,0,0,0);
  float r2 = 0.f;
  #pragma unroll
  for (int dd = 0; dd < 8; dd++){
    r.x = fmaf(ea[dd], v[dd*4+0], r.x);
    r.y = fmaf(ea[dd], v[dd*4+1], r.y);
    r.z = fmaf(ea[dd], v[dd*4+2], r.z);
    r.w = fmaf(ea[dd], v[dd*4+3], r.w);
    r2  = fmaf(ea[dd], v[32+dd], r2);
  }
  uint2 pk;
  pk.x = (unsigned int)f2bf(r.x) | ((unsigned int)f2bf(r.y) << 16);
  pk.y = (unsigned int)f2bf(r.z) | ((unsigned int)f2bf(r.w) << 16);
  *(uint2*)&ae1h[e*4] = pk;
  ae2[e] = r2;
}

__global__ __launch_bounds__(256) void k_blocksum(const int* __restrict__ cnt, int* __restrict__ bsum){
  __shared__ int sh[256];
  int n = blockIdx.x*256 + threadIdx.x;
  sh[threadIdx.x] = (n < N_NODES) ? cnt[n] : 0;
  __syncthreads();
  for (int off = 128; off > 0; off >>= 1){
    if (threadIdx.x < off) sh[threadIdx.x] += sh[threadIdx.x + off];
    __syncthreads();
  }
  if (threadIdx.x == 0) bsum[blockIdx.x] = sh[0];
}

__global__ __launch_bounds__(256) void k_scanb(const int* __restrict__ bsum, int* __restrict__ bpre){
  __shared__ int sh[256];
  int t = threadIdx.x;
  int v = (t < NB) ? bsum[t] : 0;
  sh[t] = v; __syncthreads();
  for (int off = 1; off < 256; off <<= 1){
    int u = (t >= off) ? sh[t-off] : 0;
    __syncthreads();
    sh[t] += u;
    __syncthreads();
  }
  if (t < NB) bpre[t] = sh[t] - v;
}

__global__ __launch_bounds__(256) void k_rowptr(const int* __restrict__ cnt, const int* __restrict__ bpre,
    int* __restrict__ rowptr, int* __restrict__ wofs){
  __shared__ int sh[256];
  int t = threadIdx.x; int n = blockIdx.x*256 + t;
  int c = (n < N_NODES) ? cnt[n] : 0;
  sh[t] = c; __syncthreads();
  for (int off = 1; off < 256; off <<= 1){
    int u = (t >= off) ? sh[t-off] : 0;
    __syncthreads();
    sh[t] += u;
    __syncthreads();
  }
  int incl = sh[t];
  if (n < N_NODES){
    int rp = bpre[blockIdx.x] + incl - c;
    rowptr[n] = rp;
    wofs[n] = rp;
  }
  if (n == N_NODES-1) rowptr[N_NODES] = bpre[blockIdx.x] + incl;
}

// ---- CSR fill: ONLY 8 B/edge permuted ------------------------------------
__global__ __launch_bounds__(256) void k_scatter(const int* __restrict__ src, const int* __restrict__ dst,
    int* __restrict__ wofs, int2* __restrict__ rec){
  int e = blockIdx.x*256 + threadIdx.x;
  if (e >= N_EDGES) return;
  int d = dst[e];
  int pos = atomicAdd(&wofs[d], 1);
  rec[pos] = make_int2(src[e], e);
}

// ---- GEMM1: h1 = x@W1 [N,128] (bf16 out), als1/ald1 fp32 ------------------
__global__ __launch_bounds__(256) void k_gemm1(const float* __restrict__ x, const float* __restrict__ W1,
    const float* __restrict__ as1, const float* __restrict__ ad1,
    unsigned short* __restrict__ h1b, float* __restrict__ als1, float* __restrict__ ald1){
  __shared__ float xs[64][128];  // 32 KB
  __shared__ float ws[64*128];   // 32 KB (one 64-row K-chunk of W1)
  int t = threadIdx.x;
  int cg = t & 15;               // col group: cols c8..c8+7
  int c8 = cg * 8;
  int qb = (t >> 4) * 4;         // node sub-base
  int base = blockIdx.x * 64;
  for (int i = t; i < 2048; i += 256){
    int node = base + (i >> 5);
    int col = (i & 31) * 4;
    float4 v = make_float4(0,0,0,0);
    if (node < N_NODES) v = *(const float4*)&x[node*IN_DIM + col];
    *(float4*)&xs[i>>5][col] = v;
  }
  float acc[4][8];
  #pragma unroll
  for (int q = 0; q < 4; q++)
    #pragma unroll
    for (int i = 0; i < 8; i++) acc[q][i] = 0.f;

  for (int kb = 0; kb < 128; kb += 64){
    __syncthreads();
    for (int i = t; i < 2048; i += 256)
      *(float4*)&ws[i*4] = *(const float4*)&W1[kb*128 + i*4];
    __syncthreads();
    #pragma unroll 4
    for (int k = 0; k < 64; k++){
      float4 w0 = *(float4*)&ws[k*128 + c8];
      float4 w1 = *(float4*)&ws[k*128 + c8 + 4];
      #pragma unroll
      for (int q = 0; q < 4; q++){
        float xv = xs[qb + q][kb + k];
        acc[q][0] = fmaf(xv, w0.x, acc[q][0]);
        acc[q][1] = fmaf(xv, w0.y, acc[q][1]);
        acc[q][2] = fmaf(xv, w0.z, acc[q][2]);
        acc[q][3] = fmaf(xv, w0.w, acc[q][3]);
        acc[q][4] = fmaf(xv, w1.x, acc[q][4]);
        acc[q][5] = fmaf(xv, w1.y, acc[q][5]);
        acc[q][6] = fmaf(xv, w1.z, acc[q][6]);
        acc[q][7] = fmaf(xv, w1.w, acc[q][7]);
      }
    }
  }
  int head = cg >> 2;
  float asv[8], adv[8];
  #pragma unroll
  for (int i = 0; i < 8; i++){ asv[i] = as1[c8 + i]; adv[i] = ad1[c8 + i]; }
  #pragma unroll
  for (int q = 0; q < 4; q++){
    int n = base + qb + q;
    if (n >= N_NODES) continue;
    float sa = 0.f, sd = 0.f;
    #pragma unroll
    for (int i = 0; i < 8; i++){
      sa = fmaf(acc[q][i], asv[i], sa);
      sd = fmaf(acc[q][i], adv[i], sd);
    }
    sa += __shfl_xor(sa, 1); sd += __shfl_xor(sd, 1);
    sa += __shfl_xor(sa, 2); sd += __shfl_xor(sd, 2);
    uint4 pk;
    pk.x = (unsigned int)f2bf(acc[q][0]) | ((unsigned int)f2bf(acc[q][1]) << 16);
    pk.y = (unsigned int)f2bf(acc[q][2]) | ((unsigned int)f2bf(acc[q][3]) << 16);
    pk.z = (unsigned int)f2bf(acc[q][4]) | ((unsigned int)f2bf(acc[q][5]) << 16);
    pk.w = (unsigned int)f2bf(acc[q][6]) | ((unsigned int)f2bf(acc[q][7]) << 16);
    *(uint4*)&h1b[n*HC + c8] = pk;
    if ((cg & 3) == 0){ als1[n*4 + head] = sa; ald1[n*4 + head] = sd; }
  }
}

// ---- conv1: one wave per node; bf16 payloads, fp32 logits ----------------
__global__ __launch_bounds__(256) void k_conv1(const int* __restrict__ rowptr, const int2* __restrict__ rec,
    const float* __restrict__ als1, const float* __restrict__ ald1,
    const unsigned short* __restrict__ ae1h, const unsigned short* __restrict__ h1b,
    const float* __restrict__ b1, unsigned short* __restrict__ heb){
  int wv = threadIdx.x >> 6, l = threadIdx.x & 63;
  int n = blockIdx.x*4 + wv;
  if (n >= N_NODES) return;
  int c0 = l*2, h = l >> 4;
  float ad = ald1[n*4 + h];
  float den = 0.f, sum_ae = 0.f;
  float2 acc = make_float2(0.f, 0.f);
  int r0 = rowptr[n], r1 = rowptr[n+1];
  int k = r0;
  for (; k + 2 <= r1; k += 2){
    int2 se0 = rec[k], se1 = rec[k+1];
    float ae_0 = bf2f(ae1h[se0.y*4 + h]);
    float ae_1 = bf2f(ae1h[se1.y*4 + h]);
    float as_0 = als1[se0.x*4 + h], as_1 = als1[se1.x*4 + h];
    unsigned int hv0 = *(const unsigned int*)(h1b + se0.x*HC + c0);
    unsigned int hv1 = *(const unsigned int*)(h1b + se1.x*HC + c0);
    float p0 = __expf(leaky(as_0 + ad + ae_0));
    float p1 = __expf(leaky(as_1 + ad + ae_1));
    sum_ae += ae_0 + ae_1;
    den += p0 + p1;
    acc.x = fmaf(p0, bf2f((unsigned short)hv0), acc.x);
    acc.y = fmaf(p0, bf2f((unsigned short)(hv0 >> 16)), acc.y);
    acc.x = fmaf(p1, bf2f((unsigned short)hv1), acc.x);
    acc.y = fmaf(p1, bf2f((unsigned short)(hv1 >> 16)), acc.y);
  }
  if (k < r1){
    int2 se = rec[k];
    float aev = bf2f(ae1h[se.y*4 + h]);
    float p = __expf(leaky(als1[se.x*4 + h] + ad + aev));
    unsigned int hv = *(const unsigned int*)(h1b + se.x*HC + c0);
    sum_ae += aev; den += p;
    acc.x = fmaf(p, bf2f((unsigned short)hv), acc.x);
    acc.y = fmaf(p, bf2f((unsigned short)(hv >> 16)), acc.y);
  }
  int cn = r1 - r0; if (cn < 1) cn = 1;
  float ps = __expf(leaky(als1[n*4 + h] + ad + sum_ae / (float)cn));
  unsigned int hs = *(const unsigned int*)(h1b + n*HC + c0);
  den += ps;
  acc.x = fmaf(ps, bf2f((unsigned short)hs), acc.x);
  acc.y = fmaf(ps, bf2f((unsigned short)(hs >> 16)), acc.y);
  float inv = 1.f / (den + 1e-16f);
  float o0 = elu_f(fmaf(acc.x, inv, b1[c0]));
  float o1 = elu_f(fmaf(acc.y, inv, b1[c0+1]));
  *(unsigned int*)(heb + n*HC + c0) =
      (unsigned int)f2bf(o0) | ((unsigned int)f2bf(o1) << 16);
}

// ---- GEMM2: h2 = h_elu@W2 [N,32] (bf16 in/out), als2/ald2 fp32 -----------
__global__ __launch_bounds__(256) void k_gemm2(const unsigned short* __restrict__ heb,
    const float* __restrict__ W2, const float* __restrict__ as2, const float* __restrict__ ad2,
    unsigned short* __restrict__ h2b, float* __restrict__ als2, float* __restrict__ ald2){
  __shared__ float ws[128*32];   // 16 KB full W2
  __shared__ float xs[16][128];  // 8 KB
  int t = threadIdx.x; int c = t & 31; int j = t >> 5;  // j: 0..7
  int base = blockIdx.x * 16;
  for (int i = t; i < 1024; i += 256)
    *(float4*)&ws[i*4] = *(const float4*)&W2[i*4];
  {
    int node = base + (t >> 4);
    int col = (t & 15) * 8;
    uint4 v = make_uint4(0,0,0,0);
    if (node < N_NODES) v = *(const uint4*)(heb + node*128 + col);
    float* xp = &xs[t>>4][col];
    xp[0] = bf2f((unsigned short)v.x); xp[1] = bf2f((unsigned short)(v.x>>16));
    xp[2] = bf2f((unsigned short)v.y); xp[3] = bf2f((unsigned short)(v.y>>16));
    xp[4] = bf2f((unsigned short)v.z); xp[5] = bf2f((unsigned short)(v.z>>16));
    xp[6] = bf2f((unsigned short)v.w); xp[7] = bf2f((unsigned short)(v.w>>16));
  }
  __syncthreads();
  float s0 = 0.f, s1 = 0.f;
  #pragma unroll 8
  for (int k = 0; k < 128; k++){
    float w = ws[k*32 + c];
    s0 = fmaf(xs[j*2][k],   w, s0);
    s1 = fmaf(xs[j*2+1][k], w, s1);
  }
  float a2c = as2[c], d2c = ad2[c];
  int n0 = base + j*2, n1 = n0 + 1;
  float sa0 = s0*a2c, sd0 = s0*d2c, sa1 = s1*a2c, sd1 = s1*d2c;
  #pragma unroll
  for (int off = 1; off < 32; off <<= 1){
    sa0 += __shfl_xor(sa0, off); sd0 += __shfl_xor(sd0, off);
    sa1 += __shfl_xor(sa1, off); sd1 += __shfl_xor(sd1, off);
  }
  if (n0 < N_NODES){ h2b[n0*32 + c] = f2bf(s0); if (c == 0){ als2[n0] = sa0; ald2[n0] = sd0; } }
  if (n1 < N_NODES){ h2b[n1*32 + c] = f2bf(s1); if (c == 0){ als2[n1] = sa1; ald2[n1] = sd1; } }
}

// ---- conv2: one wave per node, half-wave edge split, bf16 h2 -------------
__global__ __launch_bounds__(256) void k_conv2(const int* __restrict__ rowptr, const int2* __restrict__ rec,
    const float* __restrict__ als2, const float* __restrict__ ald2, const float* __restrict__ ae2,
    const unsigned short* __restrict__ h2b, const float* __restrict__ b2, float* __restrict__ out2){
  int wv = threadIdx.x >> 6, l = threadIdx.x & 63;
  int n = blockIdx.x*4 + wv;
  if (n >= N_NODES) return;
  int half = l >> 5, c = l & 31;
  float ad = ald2[n];
  int r0 = rowptr[n], r1 = rowptr[n+1];
  int h0 = (r1 - r0 + 1) >> 1;
  int ks = half ? r0 + h0 : r0;
  int ke = half ? r1 : r0 + h0;
  float den = 0.f, acc = 0.f, sum_ae = 0.f;
  int k = ks;
  for (; k + 2 <= ke; k += 2){
    int2 se0 = rec[k], se1 = rec[k+1];
    float ae_0 = ae2[se0.y], ae_1 = ae2[se1.y];
    float as_0 = als2[se0.x], as_1 = als2[se1.x];
    float hv0 = bf2f(h2b[se0.x*32 + c]);
    float hv1 = bf2f(h2b[se1.x*32 + c]);
    float p0 = __expf(leaky(as_0 + ad + ae_0));
    float p1 = __expf(leaky(as_1 + ad + ae_1));
    sum_ae += ae_0 + ae_1;
    den += p0 + p1;
    acc = fmaf(p0, hv0, acc);
    acc = fmaf(p1, hv1, acc);
  }
  if (k < ke){
    int2 se = rec[k];
    float aev = ae2[se.y];
    float p = __expf(leaky(als2[se.x] + ad + aev));
    float hv = bf2f(h2b[se.x*32 + c]);
    sum_ae += aev; den += p;
    acc = fmaf(p, hv, acc);
  }
  den += __shfl_xor(den, 32);
  acc += __shfl_xor(acc, 32);
  sum_ae += __shfl_xor(sum_ae, 32);
  int cn = r1 - r0; if (cn < 1) cn = 1;
  float ps = __expf(leaky(als2[n] + ad + sum_ae / (float)cn));
  den += ps;
  acc = fmaf(ps, bf2f(h2b[n*32 + c]), acc);
  float val = acc / (den + 1e-16f) + b2[c];
  if (half == 0) out2[n*32 + c] = elu_f(val);
}

// ---- global mean pool (batch is sorted) ----------------------------------
__global__ __launch_bounds__(256) void k_pool(const float* __restrict__ out2, const int* __restrict__ batch,
    float* __restrict__ gpool){
  int g = blockIdx.x;
  int a = 0, b = N_NODES;
  while (a < b){ int mid = (a + b) >> 1; if (batch[mid] < g) a = mid + 1; else b = mid; }
  int lo = a;
  a = lo; b = N_NODES;
  while (a < b){ int mid = (a + b) >> 1; if (batch[mid] < g + 1) a = mid + 1; else b = mid; }
  int hi = a;
  int t = threadIdx.x, c = t & 31, r = t >> 5;
  float s = 0.f;
  for (int n = lo + r; n < hi; n += 8) s += out2[n*32 + c];
  __shared__ float sh[256];
  sh[t] = s; __syncthreads();
  if (r == 0){
    for (int q = 1; q < 8; q++) s += sh[q*32 + c];
    int cg = hi - lo; if (cg < 1) cg = 1;
    gpool[g*32 + c] = s / (float)cg;
  }
}

// ---- MLP head ------------------------------------------------------------
__global__ __launch_bounds__(1024) void k_mlp(const float* __restrict__ gpool, const float* __restrict__ W3,
    const float* __restrict__ b3, const float* __restrict__ W4, const float* __restrict__ b4,
    float* __restrict__ out){
  __shared__ float z[64*16];
  int t = threadIdx.x;
  {
    int g = t >> 4, jj = t & 15;
    float s = b3[jj];
    #pragma unroll
    for (int c = 0; c < 32; c++) s = fmaf(gpool[g*32 + c], W3[c*16 + jj], s);
    z[t] = fmaxf(s, 0.f);
  }
  __syncthreads();
  if (t < 640){
    int g = t / 10, o = t - g*10;
    float s = b4[o];
    #pragma unroll
    for (int jj = 0; jj < 16; jj++) s = fmaf(z[g*16 + jj], W4[jj*10 + o], s);
    out[t] = s;
  }
}

extern "C" void kernel_launch(void* const* d_in, const int* in_sizes, int n_in,
                              void* d_out, int out_size, void* d_ws, size_t ws_size,
                              hipStream_t stream) {
  (void)in_sizes; (void)n_in; (void)out_size; (void)ws_size;
  const float* x     = (const float*)d_in[0];
  const int*   ei    = (const int*)  d_in[1];
  const float* eattr = (const float*)d_in[2];
  const int*   batch = (const int*)  d_in[3];
  const float* W1    = (const float*)d_in[4];
  const float* as1   = (const float*)d_in[5];
  const float* ad1   = (const float*)d_in[6];
  const float* We1   = (const float*)d_in[7];
  const float* ae1w  = (const float*)d_in[8];
  const float* b1    = (const float*)d_in[9];
  const float* W2    = (const float*)d_in[10];
  const float* as2   = (const float*)d_in[11];
  const float* ad2   = (const float*)d_in[12];
  const float* We2   = (const float*)d_in[13];
  const float* ae2w  = (const float*)d_in[14];
  const float* b2    = (const float*)d_in[15];
  const float* W3    = (const float*)d_in[16];
  const float* b3    = (const float*)d_in[17];
  const float* W4    = (const float*)d_in[18];
  const float* b4    = (const float*)d_in[19];
  float* out = (float*)d_out;
  const int* src  = ei;
  const int* dstp = ei + N_EDGES;

  char* p = (char*)d_ws;
  auto alloc = [&](size_t bytes)->void*{ void* r = (void*)p; p += (bytes + 255) & ~(size_t)255; return r; };
  int*    cnt      = (int*)   alloc(4*N_NODES);
  size_t  zero_bytes = (size_t)(p - (char*)d_ws);   // only cnt needs zeroing
  int*    wofs     = (int*)   alloc(4*N_NODES);
  int*    rowptr   = (int*)   alloc(4*(N_NODES+1));
  int*    bsum     = (int*)   alloc(4*NB);
  int*    bpre     = (int*)   alloc(4*NB);
  int2*   rec      = (int2*)  alloc(8*N_EDGES);
  float*  vbuf     = (float*) alloc(4*40);
  unsigned short* ae1h = (unsigned short*)alloc(8*N_EDGES);
  float*  ae2      = (float*) alloc(4*N_EDGES);
  unsigned short* h1b  = (unsigned short*)alloc(2*N_NODES*HC);
  float*  als1     = (float*) alloc(16*N_NODES);
  float*  ald1     = (float*) alloc(16*N_NODES);
  unsigned short* heb  = (unsigned short*)alloc(2*N_NODES*HC);
  unsigned short* h2b  = (unsigned short*)alloc(2*N_NODES*HID);
  float*  als2     = (float*) alloc(4*N_NODES);
  float*  ald2     = (float*) alloc(4*N_NODES);
  float*  out2     = (float*) alloc(4*N_NODES*HID);
  float*  gpool    = (float*) alloc(4*N_GRAPHS*HID);

  const int EB = (N_EDGES + 255)/256;   // 3125

  hipMemsetAsync(d_ws, 0, zero_bytes, stream);
  k_v       <<<1,    64,  0, stream>>>(We1, ae1w, We2, ae2w, vbuf);
  k_histae  <<<EB,   256, 0, stream>>>(dstp, eattr, vbuf, cnt, ae1h, ae2);
  k_blocksum<<<NB,   256, 0, stream>>>(cnt, bsum);
  k_scanb   <<<1,    256, 0, stream>>>(bsum, bpre);
  k_rowptr  <<<NB,   256, 0, stream>>>(cnt, bpre, rowptr, wofs);
  k_scatter <<<EB,   256, 0, stream>>>(src, dstp, wofs, rec);
  k_gemm1   <<<(N_NODES+63)/64, 256, 0, stream>>>(x, W1, as1, ad1, h1b, als1, ald1);
  k_conv1   <<<(N_NODES+3)/4, 256, 0, stream>>>(rowptr, rec, als1, ald1, ae1h, h1b, b1, heb);
  k_gemm2   <<<(N_NODES+15)/16, 256, 0, stream>>>(heb, W2, as2, ad2, h2b, als2, ald2);
  k_conv2   <<<(N_NODES+3)/4, 256, 0, stream>>>(rowptr, rec, als2, ald2, ae2, h2b, b2, out2);
  k_pool    <<<N_GRAPHS, 256, 0, stream>>>(out2, batch, gpool);
  k_mlp     <<<1,   1024, 0, stream>>>(gpool, W3, b3, W4, b4, out);
}

// Round 7
// 381.443 us; speedup vs baseline: 3.0108x; 1.0593x over previous
//
#include <hip/hip_runtime.h>
#include <hip/hip_bf16.h>
#include <math.h>

#define N_NODES 50000
#define N_EDGES 800000
#define N_GRAPHS 64
#define IN_DIM 128
#define HID 32
#define HEADS 4
#define EDGE_DIM 8
#define OUT_DIM 10
#define HC 128          // HEADS*HID
#define NB 196          // ceil(N_NODES/256)
#define EBLK 3125       // ceil(N_EDGES/256)
#define G1HALF 391      // gemm1 blocks per fused kernel (782 total)

__device__ __forceinline__ float leaky(float x){ return x >= 0.f ? x : 0.2f*x; }
__device__ __forceinline__ float elu_f(float x){ return x > 0.f ? x : __expf(x)-1.f; }

// bf16 helpers (RNE pack; payload-only quantization — attention logits stay fp32)
__device__ __forceinline__ float bf2f(unsigned short u){
  union { unsigned int i; float f; } v; v.i = ((unsigned int)u) << 16; return v.f;
}
__device__ __forceinline__ unsigned short f2bf(float f){
  union { float f; unsigned int i; } v; v.f = f;
  unsigned int r = v.i + 0x7FFF + ((v.i >> 16) & 1);
  return (unsigned short)(r >> 16);
}

// ---- GEMM1 body (shared by both fused kernels) ---------------------------
// 64 nodes/block, acc[4][8]/thread, 64 KB LDS (xs 32K + ws 32K).
__device__ __forceinline__ void gemm1_body(int bb, float* xs, float* ws,
    const float* __restrict__ x, const float* __restrict__ W1,
    const float* __restrict__ as1, const float* __restrict__ ad1,
    unsigned short* __restrict__ h1b, float* __restrict__ als1, float* __restrict__ ald1){
  int t = threadIdx.x;
  int cg = t & 15, c8 = cg*8, qb = (t >> 4)*4;
  int base = bb * 64;
  for (int i = t; i < 2048; i += 256){
    int node = base + (i >> 5);
    int col = (i & 31) * 4;
    float4 v = make_float4(0,0,0,0);
    if (node < N_NODES) v = *(const float4*)&x[node*IN_DIM + col];
    *(float4*)&xs[(i>>5)*128 + col] = v;
  }
  float acc[4][8];
  #pragma unroll
  for (int q = 0; q < 4; q++)
    #pragma unroll
    for (int i = 0; i < 8; i++) acc[q][i] = 0.f;

  for (int kb = 0; kb < 128; kb += 64){
    __syncthreads();
    for (int i = t; i < 2048; i += 256)
      *(float4*)&ws[i*4] = *(const float4*)&W1[kb*128 + i*4];
    __syncthreads();
    #pragma unroll 4
    for (int k = 0; k < 64; k++){
      float4 w0 = *(float4*)&ws[k*128 + c8];
      float4 w1 = *(float4*)&ws[k*128 + c8 + 4];
      #pragma unroll
      for (int q = 0; q < 4; q++){
        float xv = xs[(qb + q)*128 + kb + k];
        acc[q][0] = fmaf(xv, w0.x, acc[q][0]);
        acc[q][1] = fmaf(xv, w0.y, acc[q][1]);
        acc[q][2] = fmaf(xv, w0.z, acc[q][2]);
        acc[q][3] = fmaf(xv, w0.w, acc[q][3]);
        acc[q][4] = fmaf(xv, w1.x, acc[q][4]);
        acc[q][5] = fmaf(xv, w1.y, acc[q][5]);
        acc[q][6] = fmaf(xv, w1.z, acc[q][6]);
        acc[q][7] = fmaf(xv, w1.w, acc[q][7]);
      }
    }
  }
  int head = cg >> 2;
  float asv[8], adv[8];
  #pragma unroll
  for (int i = 0; i < 8; i++){ asv[i] = as1[c8 + i]; adv[i] = ad1[c8 + i]; }
  #pragma unroll
  for (int q = 0; q < 4; q++){
    int n = base + qb + q;
    if (n >= N_NODES) continue;
    float sa = 0.f, sd = 0.f;
    #pragma unroll
    for (int i = 0; i < 8; i++){
      sa = fmaf(acc[q][i], asv[i], sa);
      sd = fmaf(acc[q][i], adv[i], sd);
    }
    sa += __shfl_xor(sa, 1); sd += __shfl_xor(sd, 1);
    sa += __shfl_xor(sa, 2); sd += __shfl_xor(sd, 2);
    uint4 pk;
    pk.x = (unsigned int)f2bf(acc[q][0]) | ((unsigned int)f2bf(acc[q][1]) << 16);
    pk.y = (unsigned int)f2bf(acc[q][2]) | ((unsigned int)f2bf(acc[q][3]) << 16);
    pk.z = (unsigned int)f2bf(acc[q][4]) | ((unsigned int)f2bf(acc[q][5]) << 16);
    pk.w = (unsigned int)f2bf(acc[q][6]) | ((unsigned int)f2bf(acc[q][7]) << 16);
    *(uint4*)&h1b[n*HC + c8] = pk;
    if ((cg & 3) == 0){ als1[n*4 + head] = sa; ald1[n*4 + head] = sd; }
  }
}

// ---- FUSED 1: degree histogram (8/9 blocks) || gemm1 first half (1/9) ----
// hist is atomic/memory-bound with ~0 VALU; gemm1 is VALU/LDS-bound with
// little memory -> complementary pipes overlap on co-resident blocks.
__global__ __launch_bounds__(256) void k_f1(const int* __restrict__ dst, int* __restrict__ cnt,
    const float* __restrict__ x, const float* __restrict__ W1,
    const float* __restrict__ as1, const float* __restrict__ ad1,
    unsigned short* __restrict__ h1b, float* __restrict__ als1, float* __restrict__ ald1){
  __shared__ float smem[16384];
  int m = blockIdx.x % 9, r = blockIdx.x / 9;
  if (m < 8){
    int e = (r*8 + m)*256 + threadIdx.x;
    if (e < N_EDGES) atomicAdd(&cnt[dst[e]], 1);
    return;
  }
  gemm1_body(r, smem, smem + 8192, x, W1, as1, ad1, h1b, als1, ald1);
}

__global__ __launch_bounds__(256) void k_blocksum(const int* __restrict__ cnt, int* __restrict__ bsum){
  __shared__ int sh[256];
  int n = blockIdx.x*256 + threadIdx.x;
  sh[threadIdx.x] = (n < N_NODES) ? cnt[n] : 0;
  __syncthreads();
  for (int off = 128; off > 0; off >>= 1){
    if (threadIdx.x < off) sh[threadIdx.x] += sh[threadIdx.x + off];
    __syncthreads();
  }
  if (threadIdx.x == 0) bsum[blockIdx.x] = sh[0];
}

__global__ __launch_bounds__(256) void k_scanb(const int* __restrict__ bsum, int* __restrict__ bpre){
  __shared__ int sh[256];
  int t = threadIdx.x;
  int v = (t < NB) ? bsum[t] : 0;
  sh[t] = v; __syncthreads();
  for (int off = 1; off < 256; off <<= 1){
    int u = (t >= off) ? sh[t-off] : 0;
    __syncthreads();
    sh[t] += u;
    __syncthreads();
  }
  if (t < NB) bpre[t] = sh[t] - v;
}

__global__ __launch_bounds__(256) void k_rowptr(const int* __restrict__ cnt, const int* __restrict__ bpre,
    int* __restrict__ rowptr, int* __restrict__ wofs){
  __shared__ int sh[256];
  int t = threadIdx.x; int n = blockIdx.x*256 + t;
  int c = (n < N_NODES) ? cnt[n] : 0;
  sh[t] = c; __syncthreads();
  for (int off = 1; off < 256; off <<= 1){
    int u = (t >= off) ? sh[t-off] : 0;
    __syncthreads();
    sh[t] += u;
    __syncthreads();
  }
  int incl = sh[t];
  if (n < N_NODES){
    int rp = bpre[blockIdx.x] + incl - c;
    rowptr[n] = rp;
    wofs[n] = rp;
  }
  if (n == N_NODES-1) rowptr[N_NODES] = bpre[blockIdx.x] + incl;
}

// ---- FUSED 2: CSR scatter w/ inline edge-attention (8/9) || gemm1 2nd half
// One 16 B record per edge {src, ae1 x4 bf16, ae2 fp32} written to the
// permuted position — single small random stream (12.8 MB region).
__global__ __launch_bounds__(256) void k_f2(const int* __restrict__ src, const int* __restrict__ dst,
    const float* __restrict__ eattr,
    const float* __restrict__ We1, const float* __restrict__ ae1w,
    const float* __restrict__ We2, const float* __restrict__ ae2w,
    int* __restrict__ wofs, int4* __restrict__ rec,
    const float* __restrict__ x, const float* __restrict__ W1,
    const float* __restrict__ as1, const float* __restrict__ ad1,
    unsigned short* __restrict__ h1b, float* __restrict__ als1, float* __restrict__ ald1){
  __shared__ float smem[16384];
  int m = blockIdx.x % 9, r = blockIdx.x / 9;
  if (m < 8){
    int t = threadIdx.x;
    if (t < 32){
      int d = t >> 2, h = t & 3;
      float s = 0.f;
      for (int c = 0; c < 32; c++) s = fmaf(We1[d*128 + h*32 + c], ae1w[h*32 + c], s);
      smem[d*4 + h] = s;
    } else if (t < 40){
      int d = t - 32;
      float s = 0.f;
      for (int c = 0; c < 32; c++) s = fmaf(We2[d*32 + c], ae2w[c], s);
      smem[32 + d] = s;
    }
    __syncthreads();
    int e = (r*8 + m)*256 + t;
    if (e >= N_EDGES) return;
    int sv = src[e], d = dst[e];
    float4 x0 = *(const float4*)&eattr[e*8];
    float4 x1 = *(const float4*)&eattr[e*8+4];
    float ea[8] = {x0.x,x0.y,x0.z,x0.w,x1.x,x1.y,x1.z,x1.w};
    float4 rr = make_float4(0,0,0,0);
    float r2 = 0.f;
    #pragma unroll
    for (int dd = 0; dd < 8; dd++){
      rr.x = fmaf(ea[dd], smem[dd*4+0], rr.x);
      rr.y = fmaf(ea[dd], smem[dd*4+1], rr.y);
      rr.z = fmaf(ea[dd], smem[dd*4+2], rr.z);
      rr.w = fmaf(ea[dd], smem[dd*4+3], rr.w);
      r2   = fmaf(ea[dd], smem[32+dd], r2);
    }
    int pos = atomicAdd(&wofs[d], 1);
    int4 rv;
    rv.x = sv;
    rv.y = (int)((unsigned int)f2bf(rr.x) | ((unsigned int)f2bf(rr.y) << 16));
    rv.z = (int)((unsigned int)f2bf(rr.z) | ((unsigned int)f2bf(rr.w) << 16));
    rv.w = __float_as_int(r2);
    rec[pos] = rv;
    return;
  }
  gemm1_body(G1HALF + r, smem, smem + 8192, x, W1, as1, ad1, h1b, als1, ald1);
}

// ---- conv1: one wave per node; seq 16B records + one random row gather ---
__global__ __launch_bounds__(256) void k_conv1(const int* __restrict__ rowptr, const int4* __restrict__ rec,
    const float* __restrict__ als1, const float* __restrict__ ald1,
    const unsigned short* __restrict__ h1b, const float* __restrict__ b1,
    unsigned short* __restrict__ heb){
  int wv = threadIdx.x >> 6, l = threadIdx.x & 63;
  int n = blockIdx.x*4 + wv;
  if (n >= N_NODES) return;
  int c0 = l*2, h = l >> 4;
  int hs1 = (h & 1) * 16;
  float ad = ald1[n*4 + h];
  float den = 0.f, sum_ae = 0.f;
  float2 acc = make_float2(0.f, 0.f);
  int r0 = rowptr[n], r1 = rowptr[n+1];
  int k = r0;
  for (; k + 2 <= r1; k += 2){
    int4 q0 = rec[k], q1 = rec[k+1];
    unsigned int w0 = (h & 2) ? (unsigned int)q0.z : (unsigned int)q0.y;
    unsigned int w1 = (h & 2) ? (unsigned int)q1.z : (unsigned int)q1.y;
    float ae_0 = bf2f((unsigned short)(w0 >> hs1));
    float ae_1 = bf2f((unsigned short)(w1 >> hs1));
    float as_0 = als1[q0.x*4 + h], as_1 = als1[q1.x*4 + h];
    unsigned int hv0 = *(const unsigned int*)(h1b + q0.x*HC + c0);
    unsigned int hv1 = *(const unsigned int*)(h1b + q1.x*HC + c0);
    float p0 = __expf(leaky(as_0 + ad + ae_0));
    float p1 = __expf(leaky(as_1 + ad + ae_1));
    sum_ae += ae_0 + ae_1;
    den += p0 + p1;
    acc.x = fmaf(p0, bf2f((unsigned short)hv0), acc.x);
    acc.y = fmaf(p0, bf2f((unsigned short)(hv0 >> 16)), acc.y);
    acc.x = fmaf(p1, bf2f((unsigned short)hv1), acc.x);
    acc.y = fmaf(p1, bf2f((unsigned short)(hv1 >> 16)), acc.y);
  }
  if (k < r1){
    int4 q = rec[k];
    unsigned int w = (h & 2) ? (unsigned int)q.z : (unsigned int)q.y;
    float aev = bf2f((unsigned short)(w >> hs1));
    float p = __expf(leaky(als1[q.x*4 + h] + ad + aev));
    unsigned int hv = *(const unsigned int*)(h1b + q.x*HC + c0);
    sum_ae += aev; den += p;
    acc.x = fmaf(p, bf2f((unsigned short)hv), acc.x);
    acc.y = fmaf(p, bf2f((unsigned short)(hv >> 16)), acc.y);
  }
  int cn = r1 - r0; if (cn < 1) cn = 1;
  float ps = __expf(leaky(als1[n*4 + h] + ad + sum_ae / (float)cn));
  unsigned int hs = *(const unsigned int*)(h1b + n*HC + c0);
  den += ps;
  acc.x = fmaf(ps, bf2f((unsigned short)hs), acc.x);
  acc.y = fmaf(ps, bf2f((unsigned short)(hs >> 16)), acc.y);
  float inv = 1.f / (den + 1e-16f);
  float o0 = elu_f(fmaf(acc.x, inv, b1[c0]));
  float o1 = elu_f(fmaf(acc.y, inv, b1[c0+1]));
  *(unsigned int*)(heb + n*HC + c0) =
      (unsigned int)f2bf(o0) | ((unsigned int)f2bf(o1) << 16);
}

// ---- GEMM2: h2 = h_elu@W2 [N,32] (bf16 in/out), als2/ald2 fp32 -----------
__global__ __launch_bounds__(256) void k_gemm2(const unsigned short* __restrict__ heb,
    const float* __restrict__ W2, const float* __restrict__ as2, const float* __restrict__ ad2,
    unsigned short* __restrict__ h2b, float* __restrict__ als2, float* __restrict__ ald2){
  __shared__ float ws[128*32];   // 16 KB full W2
  __shared__ float xs[16][128];  // 8 KB
  int t = threadIdx.x; int c = t & 31; int j = t >> 5;  // j: 0..7
  int base = blockIdx.x * 16;
  for (int i = t; i < 1024; i += 256)
    *(float4*)&ws[i*4] = *(const float4*)&W2[i*4];
  {
    int node = base + (t >> 4);
    int col = (t & 15) * 8;
    uint4 v = make_uint4(0,0,0,0);
    if (node < N_NODES) v = *(const uint4*)(heb + node*128 + col);
    float* xp = &xs[t>>4][col];
    xp[0] = bf2f((unsigned short)v.x); xp[1] = bf2f((unsigned short)(v.x>>16));
    xp[2] = bf2f((unsigned short)v.y); xp[3] = bf2f((unsigned short)(v.y>>16));
    xp[4] = bf2f((unsigned short)v.z); xp[5] = bf2f((unsigned short)(v.z>>16));
    xp[6] = bf2f((unsigned short)v.w); xp[7] = bf2f((unsigned short)(v.w>>16));
  }
  __syncthreads();
  float s0 = 0.f, s1 = 0.f;
  #pragma unroll 8
  for (int k = 0; k < 128; k++){
    float w = ws[k*32 + c];
    s0 = fmaf(xs[j*2][k],   w, s0);
    s1 = fmaf(xs[j*2+1][k], w, s1);
  }
  float a2c = as2[c], d2c = ad2[c];
  int n0 = base + j*2, n1 = n0 + 1;
  float sa0 = s0*a2c, sd0 = s0*d2c, sa1 = s1*a2c, sd1 = s1*d2c;
  #pragma unroll
  for (int off = 1; off < 32; off <<= 1){
    sa0 += __shfl_xor(sa0, off); sd0 += __shfl_xor(sd0, off);
    sa1 += __shfl_xor(sa1, off); sd1 += __shfl_xor(sd1, off);
  }
  if (n0 < N_NODES){ h2b[n0*32 + c] = f2bf(s0); if (c == 0){ als2[n0] = sa0; ald2[n0] = sd0; } }
  if (n1 < N_NODES){ h2b[n1*32 + c] = f2bf(s1); if (c == 0){ als2[n1] = sa1; ald2[n1] = sd1; } }
}

// ---- conv2: one wave per node, half-wave edge split, bf16 h2 -------------
__global__ __launch_bounds__(256) void k_conv2(const int* __restrict__ rowptr, const int4* __restrict__ rec,
    const float* __restrict__ als2, const float* __restrict__ ald2,
    const unsigned short* __restrict__ h2b, const float* __restrict__ b2, float* __restrict__ out2){
  int wv = threadIdx.x >> 6, l = threadIdx.x & 63;
  int n = blockIdx.x*4 + wv;
  if (n >= N_NODES) return;
  int half = l >> 5, c = l & 31;
  float ad = ald2[n];
  int r0 = rowptr[n], r1 = rowptr[n+1];
  int h0 = (r1 - r0 + 1) >> 1;
  int ks = half ? r0 + h0 : r0;
  int ke = half ? r1 : r0 + h0;
  float den = 0.f, acc = 0.f, sum_ae = 0.f;
  int k = ks;
  for (; k + 2 <= ke; k += 2){
    int4 q0 = rec[k], q1 = rec[k+1];
    float ae_0 = __int_as_float(q0.w), ae_1 = __int_as_float(q1.w);
    float as_0 = als2[q0.x], as_1 = als2[q1.x];
    float hv0 = bf2f(h2b[q0.x*32 + c]);
    float hv1 = bf2f(h2b[q1.x*32 + c]);
    float p0 = __expf(leaky(as_0 + ad + ae_0));
    float p1 = __expf(leaky(as_1 + ad + ae_1));
    sum_ae += ae_0 + ae_1;
    den += p0 + p1;
    acc = fmaf(p0, hv0, acc);
    acc = fmaf(p1, hv1, acc);
  }
  if (k < ke){
    int4 q = rec[k];
    float aev = __int_as_float(q.w);
    float p = __expf(leaky(als2[q.x] + ad + aev));
    float hv = bf2f(h2b[q.x*32 + c]);
    sum_ae += aev; den += p;
    acc = fmaf(p, hv, acc);
  }
  den += __shfl_xor(den, 32);
  acc += __shfl_xor(acc, 32);
  sum_ae += __shfl_xor(sum_ae, 32);
  int cn = r1 - r0; if (cn < 1) cn = 1;
  float ps = __expf(leaky(als2[n] + ad + sum_ae / (float)cn));
  den += ps;
  acc = fmaf(ps, bf2f(h2b[n*32 + c]), acc);
  float val = acc / (den + 1e-16f) + b2[c];
  if (half == 0) out2[n*32 + c] = elu_f(val);
}

// ---- global mean pool (batch is sorted) ----------------------------------
__global__ __launch_bounds__(256) void k_pool(const float* __restrict__ out2, const int* __restrict__ batch,
    float* __restrict__ gpool){
  int g = blockIdx.x;
  int a = 0, b = N_NODES;
  while (a < b){ int mid = (a + b) >> 1; if (batch[mid] < g) a = mid + 1; else b = mid; }
  int lo = a;
  a = lo; b = N_NODES;
  while (a < b){ int mid = (a + b) >> 1; if (batch[mid] < g + 1) a = mid + 1; else b = mid; }
  int hi = a;
  int t = threadIdx.x, c = t & 31, r = t >> 5;
  float s = 0.f;
  for (int n = lo + r; n < hi; n += 8) s += out2[n*32 + c];
  __shared__ float sh[256];
  sh[t] = s; __syncthreads();
  if (r == 0){
    for (int q = 1; q < 8; q++) s += sh[q*32 + c];
    int cg = hi - lo; if (cg < 1) cg = 1;
    gpool[g*32 + c] = s / (float)cg;
  }
}

// ---- MLP head ------------------------------------------------------------
__global__ __launch_bounds__(1024) void k_mlp(const float* __restrict__ gpool, const float* __restrict__ W3,
    const float* __restrict__ b3, const float* __restrict__ W4, const float* __restrict__ b4,
    float* __restrict__ out){
  __shared__ float z[64*16];
  int t = threadIdx.x;
  {
    int g = t >> 4, jj = t & 15;
    float s = b3[jj];
    #pragma unroll
    for (int c = 0; c < 32; c++) s = fmaf(gpool[g*32 + c], W3[c*16 + jj], s);
    z[t] = fmaxf(s, 0.f);
  }
  __syncthreads();
  if (t < 640){
    int g = t / 10, o = t - g*10;
    float s = b4[o];
    #pragma unroll
    for (int jj = 0; jj < 16; jj++) s = fmaf(z[g*16 + jj], W4[jj*10 + o], s);
    out[t] = s;
  }
}

extern "C" void kernel_launch(void* const* d_in, const int* in_sizes, int n_in,
                              void* d_out, int out_size, void* d_ws, size_t ws_size,
                              hipStream_t stream) {
  (void)in_sizes; (void)n_in; (void)out_size; (void)ws_size;
  const float* x     = (const float*)d_in[0];
  const int*   ei    = (const int*)  d_in[1];
  const float* eattr = (const float*)d_in[2];
  const int*   batch = (const int*)  d_in[3];
  const float* W1    = (const float*)d_in[4];
  const float* as1   = (const float*)d_in[5];
  const float* ad1   = (const float*)d_in[6];
  const float* We1   = (const float*)d_in[7];
  const float* ae1w  = (const float*)d_in[8];
  const float* b1    = (const float*)d_in[9];
  const float* W2    = (const float*)d_in[10];
  const float* as2   = (const float*)d_in[11];
  const float* ad2   = (const float*)d_in[12];
  const float* We2   = (const float*)d_in[13];
  const float* ae2w  = (const float*)d_in[14];
  const float* b2    = (const float*)d_in[15];
  const float* W3    = (const float*)d_in[16];
  const float* b3    = (const float*)d_in[17];
  const float* W4    = (const float*)d_in[18];
  const float* b4    = (const float*)d_in[19];
  float* out = (float*)d_out;
  const int* src  = ei;
  const int* dstp = ei + N_EDGES;

  char* p = (char*)d_ws;
  auto alloc = [&](size_t bytes)->void*{ void* r = (void*)p; p += (bytes + 255) & ~(size_t)255; return r; };
  int*    cnt      = (int*)   alloc(4*N_NODES);
  size_t  zero_bytes = (size_t)(p - (char*)d_ws);   // only cnt needs zeroing
  int*    wofs     = (int*)   alloc(4*N_NODES);
  int*    rowptr   = (int*)   alloc(4*(N_NODES+1));
  int*    bsum     = (int*)   alloc(4*NB);
  int*    bpre     = (int*)   alloc(4*NB);
  int4*   rec      = (int4*)  alloc(16*N_EDGES);
  unsigned short* h1b  = (unsigned short*)alloc(2*N_NODES*HC);
  float*  als1     = (float*) alloc(16*N_NODES);
  float*  ald1     = (float*) alloc(16*N_NODES);
  unsigned short* heb  = (unsigned short*)alloc(2*N_NODES*HC);
  unsigned short* h2b  = (unsigned short*)alloc(2*N_NODES*HID);
  float*  als2     = (float*) alloc(4*N_NODES);
  float*  ald2     = (float*) alloc(4*N_NODES);
  float*  out2     = (float*) alloc(4*N_NODES*HID);
  float*  gpool    = (float*) alloc(4*N_GRAPHS*HID);

  const int FGRID = G1HALF * 9;   // 3519: 8/9 atomic blocks + 1/9 gemm1 blocks

  hipMemsetAsync(d_ws, 0, zero_bytes, stream);
  k_f1      <<<FGRID, 256, 0, stream>>>(dstp, cnt, x, W1, as1, ad1, h1b, als1, ald1);
  k_blocksum<<<NB,    256, 0, stream>>>(cnt, bsum);
  k_scanb   <<<1,     256, 0, stream>>>(bsum, bpre);
  k_rowptr  <<<NB,    256, 0, stream>>>(cnt, bpre, rowptr, wofs);
  k_f2      <<<FGRID, 256, 0, stream>>>(src, dstp, eattr, We1, ae1w, We2, ae2w,
                                        wofs, rec, x, W1, as1, ad1, h1b, als1, ald1);
  k_conv1   <<<(N_NODES+3)/4, 256, 0, stream>>>(rowptr, rec, als1, ald1, h1b, b1, heb);
  k_gemm2   <<<(N_NODES+15)/16, 256, 0, stream>>>(heb, W2, as2, ad2, h2b, als2, ald2);
  k_conv2   <<<(N_NODES+3)/4, 256, 0, stream>>>(rowptr, rec, als2, ald2, h2b, b2, out2);
  k_pool    <<<N_GRAPHS, 256, 0, stream>>>(out2, batch, gpool);
  k_mlp     <<<1,    1024, 0, stream>>>(gpool, W3, b3, W4, b4, out);
}